// Round 1
// baseline (31012.711 us; speedup 1.0000x reference)
//
#include <hip/hip_runtime.h>
#include <hip/hip_bf16.h>

// Problem constants
#define BQ    8192          // batch
#define FIN   12288         // C*S1*S2
#define SUN   4096          // s_units
#define HIDN  1024          // hidden_size
#define XW    2048          // 2*HID
#define NDOM  8
#define H1N   28
#define H2N   14
#define NWAY  5
#define BN_EPS 1e-5f
#define LEAKS 0.001f

// ---------------------------------------------------------------------------
// Generic fp32 GEMM: C[M,N] = act(A[M,K] @ B[K,N] + bias[N])
// 64x64 block tile, BK=32, 256 threads, 4x4 micro-tile.
// Optional device-side domain offset (for Wp/bp gather by domain_id).
// ACT: 0=none, 1=relu, 2=leaky(0.001)
// ---------------------------------------------------------------------------
#define BKK 32

template<int ACT>
__global__ __launch_bounds__(256) void gemm64(
    const float* __restrict__ A, const float* __restrict__ B,
    const float* __restrict__ bias, float* __restrict__ C,
    int M, int N, int K, int ldc, int cc0,
    const int* __restrict__ dom, long long bStride, int biasStride)
{
    if (dom != nullptr) {
        int d = *dom;
        B    += (size_t)d * (size_t)bStride;
        bias += (size_t)d * (size_t)biasStride;
    }
    __shared__ alignas(16) float as[BKK][68];   // [k][row], padded
    __shared__ alignas(16) float bs[BKK][68];   // [k][col], padded

    const int t   = threadIdx.x;
    const int tx  = t & 15;          // 0..15 -> 4 cols each
    const int ty  = t >> 4;          // 0..15 -> 4 rows each
    const int row0 = blockIdx.y * 64;
    const int col0 = blockIdx.x * 64;

    // staging indices
    const int akk  = (t & 7) * 4;    // k offset 0..28
    const int arow = t >> 3;         // 0..31 (and +32 second pass)
    const int bcc  = (t & 15) * 4;   // col offset 0..60
    const int bk   = t >> 4;         // 0..15 (and +16 second pass)

    const float* Aptr = A + (size_t)(row0 + arow) * K + akk;
    const float* Bptr = B + (size_t)bk * N + col0 + bcc;

    float acc[4][4] = {{0.f,0.f,0.f,0.f},{0.f,0.f,0.f,0.f},
                       {0.f,0.f,0.f,0.f},{0.f,0.f,0.f,0.f}};

    for (int k0 = 0; k0 < K; k0 += BKK) {
        const float4 a0 = *(const float4*)(Aptr + k0);
        const float4 a1 = *(const float4*)(Aptr + (size_t)32 * K + k0);
        const float4 b0 = *(const float4*)(Bptr + (size_t)k0 * N);
        const float4 b1 = *(const float4*)(Bptr + (size_t)(k0 + 16) * N);

        __syncthreads();   // previous tile fully consumed
        as[akk+0][arow]    = a0.x; as[akk+1][arow]    = a0.y;
        as[akk+2][arow]    = a0.z; as[akk+3][arow]    = a0.w;
        as[akk+0][arow+32] = a1.x; as[akk+1][arow+32] = a1.y;
        as[akk+2][arow+32] = a1.z; as[akk+3][arow+32] = a1.w;
        *(float4*)&bs[bk][bcc]      = b0;
        *(float4*)&bs[bk+16][bcc]   = b1;
        __syncthreads();

        #pragma unroll
        for (int k = 0; k < BKK; ++k) {
            const float4 av = *(const float4*)&as[k][ty*4];
            const float4 bv = *(const float4*)&bs[k][tx*4];
            const float ar[4] = {av.x, av.y, av.z, av.w};
            const float br[4] = {bv.x, bv.y, bv.z, bv.w};
            #pragma unroll
            for (int i = 0; i < 4; ++i)
                #pragma unroll
                for (int j = 0; j < 4; ++j)
                    acc[i][j] = fmaf(ar[i], br[j], acc[i][j]);
        }
    }

    const float* bptr = bias + col0 + tx*4;
    const float bvals[4] = {bptr[0], bptr[1], bptr[2], bptr[3]};
    #pragma unroll
    for (int i = 0; i < 4; ++i) {
        float vv[4];
        #pragma unroll
        for (int j = 0; j < 4; ++j) {
            float x = acc[i][j] + bvals[j];
            if (ACT == 1)      x = fmaxf(x, 0.f);
            else if (ACT == 2) x = (x > 0.f) ? x : LEAKS * x;
            vv[j] = x;
        }
        float4 v; v.x = vv[0]; v.y = vv[1]; v.z = vv[2]; v.w = vv[3];
        *(float4*)&C[(size_t)(row0 + ty*4 + i) * ldc + cc0 + col0 + tx*4] = v;
    }
}

// ---------------------------------------------------------------------------
// BatchNorm stage A: partial column sums/sumsq over 256-row blocks.
// grid = (XW/256, 32), block = 256. X is [BQ][XW] row-major.
// ---------------------------------------------------------------------------
__global__ __launch_bounds__(256) void bn_stats_a(
    const float* __restrict__ X, float* __restrict__ psum, float* __restrict__ pss)
{
    const int c  = blockIdx.x * 256 + threadIdx.x;   // column 0..2047
    const int rb = blockIdx.y;                       // row block 0..31
    float s = 0.f, ss = 0.f;
    const int r0 = rb * 256;
    for (int r = r0; r < r0 + 256; ++r) {
        float v = X[(size_t)r * XW + c];
        s += v; ss = fmaf(v, v, ss);
    }
    psum[rb * XW + c] = s;
    pss [rb * XW + c] = ss;
}

// Stage B: finalize -> per-feature scale/shift.  grid = XW/256.
__global__ __launch_bounds__(256) void bn_stats_b(
    const float* __restrict__ psum, const float* __restrict__ pss,
    const float* __restrict__ gamma, const float* __restrict__ beta,
    float* __restrict__ scale, float* __restrict__ shift)
{
    const int c = blockIdx.x * 256 + threadIdx.x;
    float s = 0.f, ss = 0.f;
    for (int rb = 0; rb < 32; ++rb) { s += psum[rb * XW + c]; ss += pss[rb * XW + c]; }
    const float inv = 1.f / (float)BQ;
    const float mean = s * inv;
    const float var  = ss * inv - mean * mean;   // biased variance (ddof=0)
    const float sc = gamma[c] * rsqrtf(var + BN_EPS);
    scale[c] = sc;
    shift[c] = beta[c] - mean * sc;
}

// ---------------------------------------------------------------------------
// Heads: per-sample task-routed 3-layer MLP. One wave per sample.
// x normalized (scale/shift) into LDS; lanes own output features so the
// Wh streams are read coalesced (28/14/5 consecutive floats per step).
// ---------------------------------------------------------------------------
__global__ __launch_bounds__(256) void head_kernel(
    const float* __restrict__ X, const float* __restrict__ scale,
    const float* __restrict__ shift, const int* __restrict__ tt,
    const float* __restrict__ Wh1, const float* __restrict__ bh1,
    const float* __restrict__ Wh2, const float* __restrict__ bh2,
    const float* __restrict__ Wh3, const float* __restrict__ bh3,
    float* __restrict__ out)
{
    __shared__ float xs[4][XW];
    __shared__ float y1[4][H1N];
    __shared__ float y2[4][H2N + 2];

    const int t = threadIdx.x;
    const int w = t >> 6;            // wave 0..3
    const int l = t & 63;            // lane
    const int s = blockIdx.x * 4 + w;
    const int d = tt[s];

    // stage normalized x (coalesced)
    #pragma unroll 4
    for (int i = 0; i < XW / 64; ++i) {
        const int c = i * 64 + l;
        xs[w][c] = fmaf(X[(size_t)s * XW + c], scale[c], shift[c]);
    }
    __syncthreads();

    // head 1: 2048 -> 28, relu
    if (l < H1N) {
        const float* W1 = Wh1 + (size_t)d * XW * H1N;
        float acc = bh1[d * H1N + l];
        #pragma unroll 8
        for (int c = 0; c < XW; ++c)
            acc = fmaf(xs[w][c], W1[c * H1N + l], acc);
        y1[w][l] = fmaxf(acc, 0.f);
    }
    __syncthreads();

    // head 2: 28 -> 14, relu
    if (l < H2N) {
        const float* W2 = Wh2 + (size_t)d * H1N * H2N;
        float acc = bh2[d * H2N + l];
        #pragma unroll
        for (int c = 0; c < H1N; ++c)
            acc = fmaf(y1[w][c], W2[c * H2N + l], acc);
        y2[w][l] = fmaxf(acc, 0.f);
    }
    __syncthreads();

    // head 3: 14 -> 5, linear
    if (l < NWAY) {
        const float* W3 = Wh3 + (size_t)d * H2N * NWAY;
        float acc = bh3[d * NWAY + l];
        #pragma unroll
        for (int c = 0; c < H2N; ++c)
            acc = fmaf(y2[w][c], W3[c * NWAY + l], acc);
        out[(size_t)s * NWAY + l] = acc;
    }
}

// ---------------------------------------------------------------------------
extern "C" void kernel_launch(void* const* d_in, const int* in_sizes, int n_in,
                              void* d_out, int out_size, void* d_ws, size_t ws_size,
                              hipStream_t stream)
{
    const float* x_s   = (const float*)d_in[0];
    const float* x_p   = (const float*)d_in[1];
    const int*   tt    = (const int*)  d_in[2];
    const int*   dom   = (const int*)  d_in[3];
    const float* W_in  = (const float*)d_in[4];
    const float* b_in  = (const float*)d_in[5];
    const float* W_hid = (const float*)d_in[6];
    const float* b_hid = (const float*)d_in[7];
    const float* W_out = (const float*)d_in[8];
    const float* b_out = (const float*)d_in[9];
    const float* Wp    = (const float*)d_in[10];
    const float* bp    = (const float*)d_in[11];
    const float* gamma = (const float*)d_in[12];
    const float* beta  = (const float*)d_in[13];
    const float* Wh1   = (const float*)d_in[14];
    const float* bh1   = (const float*)d_in[15];
    const float* Wh2   = (const float*)d_in[16];
    const float* bh2   = (const float*)d_in[17];
    const float* Wh3   = (const float*)d_in[18];
    const float* bh3   = (const float*)d_in[19];
    float* out = (float*)d_out;

    // workspace layout (total = 256 MiB):
    //   bufA: [8192][4096] f32  (134217728 B)
    //   bufB: [8192][4096] f32  (134217728 B); X=[8192][2048] lives in first half,
    //         BN stats live in second half of bufB (only used after X is final)
    char* w = (char*)d_ws;
    float* bufA  = (float*)w;
    float* bufB  = (float*)(w + 134217728);
    float* psum  = bufB + (size_t)BQ * XW;           // 32*2048 floats
    float* pss   = psum + 32 * XW;
    float* scale = pss  + 32 * XW;
    float* shift = scale + XW;

    const dim3 blk(256);

    // shared branch: in -> 4x hid -> out (relu everywhere)
    gemm64<1><<<dim3(SUN/64,  BQ/64), blk, 0, stream>>>(x_s,  W_in,  b_in,  bufA, BQ, SUN,  FIN, SUN, 0, nullptr, 0, 0);
    gemm64<1><<<dim3(SUN/64,  BQ/64), blk, 0, stream>>>(bufA, W_hid, b_hid, bufB, BQ, SUN,  SUN, SUN, 0, nullptr, 0, 0);
    gemm64<1><<<dim3(SUN/64,  BQ/64), blk, 0, stream>>>(bufB, W_hid, b_hid, bufA, BQ, SUN,  SUN, SUN, 0, nullptr, 0, 0);
    gemm64<1><<<dim3(SUN/64,  BQ/64), blk, 0, stream>>>(bufA, W_hid, b_hid, bufB, BQ, SUN,  SUN, SUN, 0, nullptr, 0, 0);
    gemm64<1><<<dim3(SUN/64,  BQ/64), blk, 0, stream>>>(bufB, W_hid, b_hid, bufA, BQ, SUN,  SUN, SUN, 0, nullptr, 0, 0);
    // h_shared -> X[:, 0:1024]
    gemm64<1><<<dim3(HIDN/64, BQ/64), blk, 0, stream>>>(bufA, W_out, b_out, bufB, BQ, HIDN, SUN, XW, 0, nullptr, 0, 0);
    // private branch (domain-gathered W/b, leaky relu) -> X[:, 1024:2048]
    gemm64<2><<<dim3(HIDN/64, BQ/64), blk, 0, stream>>>(x_p, Wp, bp, bufB, BQ, HIDN, FIN, XW, HIDN,
                                                        dom, (long long)FIN * HIDN, HIDN);

    // batchnorm statistics -> scale/shift
    bn_stats_a<<<dim3(XW/256, 32), blk, 0, stream>>>(bufB, psum, pss);
    bn_stats_b<<<dim3(XW/256),     blk, 0, stream>>>(psum, pss, gamma, beta, scale, shift);

    // task-routed heads (BN applied on load)
    head_kernel<<<dim3(BQ/4), blk, 0, stream>>>(bufB, scale, shift, tt,
                                                Wh1, bh1, Wh2, bh2, Wh3, bh3, out);
}

// Round 2
// 3806.118 us; speedup vs baseline: 8.1481x; 8.1481x over previous
//
#include <hip/hip_runtime.h>
#include <hip/hip_bf16.h>

// Problem constants
#define BQ    8192
#define FIN   12288
#define SUN   4096
#define HIDN  1024
#define XW    2048
#define H1N   28
#define H2N   14
#define NWAY  5
#define BN_EPS 1e-5f
#define LEAKS 0.001f

typedef __bf16 bf16x8 __attribute__((ext_vector_type(8)));
typedef float  f32x4  __attribute__((ext_vector_type(4)));
typedef unsigned short ushort8 __attribute__((ext_vector_type(8)));

__device__ __forceinline__ unsigned short f2bf(float f) {
    unsigned u = __float_as_uint(f);
    unsigned r = u + 0x7fffu + ((u >> 16) & 1u);   // RNE
    return (unsigned short)(r >> 16);
}

#define TO_LDS(p) ((__attribute__((address_space(3))) void*)(p))
#define TO_GLB(p) ((const __attribute__((address_space(1))) void*)(p))

// ---------------------------------------------------------------------------
// Transpose + fp32->bf16 convert:  in[R][Cc] f32  ->  out[Cc][R] bf16
// 64x64 tiles via padded LDS. Optional device-side domain offset on input.
// grid = (Cc/64, R/64), block = 256.
// ---------------------------------------------------------------------------
__global__ __launch_bounds__(256) void transpose_cvt(
    const float* __restrict__ in, unsigned short* __restrict__ out,
    int R, int Cc, const int* __restrict__ dom)
{
    if (dom) in += (size_t)(*dom) * (size_t)R * (size_t)Cc;
    __shared__ float tile[64][65];
    const int t  = threadIdx.x;
    const int tr = t >> 4;          // 0..15
    const int tc = t & 15;          // 0..15
    const int c0 = blockIdx.x * 64;
    const int r0 = blockIdx.y * 64;

    #pragma unroll
    for (int q = 0; q < 4; ++q) {
        const int r = r0 + tr + q * 16;
        const float4 v = *(const float4*)&in[(size_t)r * Cc + c0 + tc * 4];
        tile[tc*4+0][tr + q*16] = v.x;
        tile[tc*4+1][tr + q*16] = v.y;
        tile[tc*4+2][tr + q*16] = v.z;
        tile[tc*4+3][tr + q*16] = v.w;
    }
    __syncthreads();
    #pragma unroll
    for (int q = 0; q < 4; ++q) {
        const int c = c0 + tr + q * 16;     // output row (N dim)
        ushort4 o;
        o.x = f2bf(tile[tr + q*16][tc*4+0]);
        o.y = f2bf(tile[tr + q*16][tc*4+1]);
        o.z = f2bf(tile[tr + q*16][tc*4+2]);
        o.w = f2bf(tile[tr + q*16][tc*4+3]);
        *(ushort4*)&out[(size_t)c * R + r0 + tc * 4] = o;
    }
}

// ---------------------------------------------------------------------------
// bf16 MFMA GEMM, m97 structure.
//   C[M,N] = act(A[M,K] @ W[K,N] + bias[N]),  B given TRANSPOSED: Bt[N][K] bf16
//   128x128 tile, BK=32, 256 thr = 4 waves (2x2), 64x64 per wave,
//   mfma_f32_16x16x32_bf16, 4x4 fragments per wave.
// A_F32: A is fp32, reg-staged with convert. else A bf16 via global_load_lds.
// OUT_F32: write C as fp32 (for X), else bf16.
// ACT: 0 none, 1 relu, 2 leaky(0.001)
// ---------------------------------------------------------------------------
template<bool A_F32, bool OUT_F32, int ACT>
__global__ __launch_bounds__(256) void gemm_mfma(
    const void* __restrict__ Ap, const unsigned short* __restrict__ Bt,
    const float* __restrict__ bias, void* __restrict__ Cp,
    int M, int N, int K, int ldc, int cc0,
    const int* __restrict__ dom, int biasStride)
{
    __shared__ alignas(16) unsigned short As[128 * 32];   // [row m][k] 8KB
    __shared__ alignas(16) unsigned short Bs[128 * 32];   // [row n][k] 8KB

    const int nbx = N >> 7;
    int wg = blockIdx.x;
    const int nwg = gridDim.x;
    if ((nwg & 7) == 0) {                     // bijective XCD swizzle
        const int cpx = nwg >> 3;
        wg = (wg & 7) * cpx + (wg >> 3);
    }
    const int bx = wg % nbx, by = wg / nbx;
    const int row0 = by << 7, col0 = bx << 7;

    const int t  = threadIdx.x;
    const int w  = t >> 6;                    // wave 0..3
    const int l  = t & 63;
    const int wr = w >> 1, wc = w & 1;        // wave 2x2
    const int lr = l & 15, lk = l >> 4;       // fragment lane decomposition

    f32x4 acc[4][4];
    #pragma unroll
    for (int i = 0; i < 4; ++i)
        #pragma unroll
        for (int j = 0; j < 4; ++j)
            acc[i][j] = (f32x4)(0.f);

    // staging constants
    const int srow = l >> 2;                  // 0..15 within 16-row chunk
    const int skb  = (l & 3) * 16;            // byte offset within 64B row
    const float* Af = (const float*)Ap;
    const unsigned short* Ab = (const unsigned short*)Ap;

    for (int k0 = 0; k0 < K; k0 += 32) {
        __syncthreads();      // prev tile fully consumed (ds_reads retired)

        // ---- stage B: 2 global_load_lds per wave (wave-uniform LDS base) ----
        #pragma unroll
        for (int c = 0; c < 2; ++c) {
            const int inst = w * 2 + c;                  // 0..7
            const int row  = inst * 16 + srow;           // n-row 0..127
            const char* src = (const char*)Bt +
                (((size_t)(col0 + row) * K + k0) * 2 + skb);
            char* dst = (char*)Bs + inst * 1024;
            __builtin_amdgcn_global_load_lds(TO_GLB(src), TO_LDS(dst), 16, 0, 0);
        }
        // ---- stage A ----
        if (!A_F32) {
            #pragma unroll
            for (int c = 0; c < 2; ++c) {
                const int inst = w * 2 + c;
                const int row  = inst * 16 + srow;
                const char* src = (const char*)Ab +
                    (((size_t)(row0 + row) * K + k0) * 2 + skb);
                char* dst = (char*)As + inst * 1024;
                __builtin_amdgcn_global_load_lds(TO_GLB(src), TO_LDS(dst), 16, 0, 0);
            }
        } else {
            #pragma unroll
            for (int c = 0; c < 2; ++c) {
                const int ci  = t + 256 * c;             // 16B chunk id
                const int row = ci >> 2;                 // m-row 0..127
                const int ko  = (ci & 3) * 8;            // k elem offset
                const float* s = Af + (size_t)(row0 + row) * K + k0 + ko;
                const float4 v0 = *(const float4*)s;
                const float4 v1 = *(const float4*)(s + 4);
                ushort8 p;
                p[0]=f2bf(v0.x); p[1]=f2bf(v0.y); p[2]=f2bf(v0.z); p[3]=f2bf(v0.w);
                p[4]=f2bf(v1.x); p[5]=f2bf(v1.y); p[6]=f2bf(v1.z); p[7]=f2bf(v1.w);
                *(ushort8*)&As[ci * 8] = p;
            }
        }
        __syncthreads();      // drains vmcnt/lgkmcnt -> staged data visible

        // ---- fragments + 16 MFMA ----
        bf16x8 af[4], bfv[4];
        #pragma unroll
        for (int i = 0; i < 4; ++i)
            af[i]  = *(const bf16x8*)&As[(wr*64 + i*16 + lr) * 32 + lk * 8];
        #pragma unroll
        for (int j = 0; j < 4; ++j)
            bfv[j] = *(const bf16x8*)&Bs[(wc*64 + j*16 + lr) * 32 + lk * 8];
        #pragma unroll
        for (int i = 0; i < 4; ++i)
            #pragma unroll
            for (int j = 0; j < 4; ++j)
                acc[i][j] = __builtin_amdgcn_mfma_f32_16x16x32_bf16(
                    af[i], bfv[j], acc[i][j], 0, 0, 0);
    }

    // ---- epilogue: bias + act + store ----
    if (dom) bias += (*dom) * biasStride;
    const int colb = col0 + wc * 64 + lr;     // + j*16
    const int rowb = row0 + wr * 64 + lk * 4; // + i*16 + r
    float bj[4];
    #pragma unroll
    for (int j = 0; j < 4; ++j) bj[j] = bias[colb + j * 16];

    #pragma unroll
    for (int i = 0; i < 4; ++i) {
        #pragma unroll
        for (int r = 0; r < 4; ++r) {
            const size_t row = rowb + i * 16 + r;
            #pragma unroll
            for (int j = 0; j < 4; ++j) {
                float x = acc[i][j][r] + bj[j];
                if (ACT == 1)      x = fmaxf(x, 0.f);
                else if (ACT == 2) x = (x > 0.f) ? x : LEAKS * x;
                const size_t idx = row * (size_t)ldc + cc0 + colb + j * 16;
                if (OUT_F32) ((float*)Cp)[idx] = x;
                else         ((unsigned short*)Cp)[idx] = f2bf(x);
            }
        }
    }
}

// ---------------------------------------------------------------------------
// BatchNorm stats (X fp32 [BQ][XW]) — unchanged from round 1.
// ---------------------------------------------------------------------------
__global__ __launch_bounds__(256) void bn_stats_a(
    const float* __restrict__ X, float* __restrict__ psum, float* __restrict__ pss)
{
    const int c  = blockIdx.x * 256 + threadIdx.x;
    const int rb = blockIdx.y;
    float s = 0.f, ss = 0.f;
    const int r0 = rb * 256;
    for (int r = r0; r < r0 + 256; ++r) {
        float v = X[(size_t)r * XW + c];
        s += v; ss = fmaf(v, v, ss);
    }
    psum[rb * XW + c] = s;
    pss [rb * XW + c] = ss;
}

__global__ __launch_bounds__(256) void bn_stats_b(
    const float* __restrict__ psum, const float* __restrict__ pss,
    const float* __restrict__ gamma, const float* __restrict__ beta,
    float* __restrict__ scale, float* __restrict__ shift)
{
    const int c = blockIdx.x * 256 + threadIdx.x;
    float s = 0.f, ss = 0.f;
    for (int rb = 0; rb < 32; ++rb) { s += psum[rb * XW + c]; ss += pss[rb * XW + c]; }
    const float inv = 1.f / (float)BQ;
    const float mean = s * inv;
    const float var  = ss * inv - mean * mean;
    const float sc = gamma[c] * rsqrtf(var + BN_EPS);
    scale[c] = sc;
    shift[c] = beta[c] - mean * sc;
}

// ---------------------------------------------------------------------------
// Heads — unchanged from round 1 (fp32 X, fp32 weights).
// ---------------------------------------------------------------------------
__global__ __launch_bounds__(256) void head_kernel(
    const float* __restrict__ X, const float* __restrict__ scale,
    const float* __restrict__ shift, const int* __restrict__ tt,
    const float* __restrict__ Wh1, const float* __restrict__ bh1,
    const float* __restrict__ Wh2, const float* __restrict__ bh2,
    const float* __restrict__ Wh3, const float* __restrict__ bh3,
    float* __restrict__ out)
{
    __shared__ float xs[4][XW];
    __shared__ float y1[4][H1N];
    __shared__ float y2[4][H2N + 2];

    const int t = threadIdx.x;
    const int w = t >> 6;
    const int l = t & 63;
    const int s = blockIdx.x * 4 + w;
    const int d = tt[s];

    #pragma unroll 4
    for (int i = 0; i < XW / 64; ++i) {
        const int c = i * 64 + l;
        xs[w][c] = fmaf(X[(size_t)s * XW + c], scale[c], shift[c]);
    }
    __syncthreads();

    if (l < H1N) {
        const float* W1 = Wh1 + (size_t)d * XW * H1N;
        float acc = bh1[d * H1N + l];
        #pragma unroll 8
        for (int c = 0; c < XW; ++c)
            acc = fmaf(xs[w][c], W1[c * H1N + l], acc);
        y1[w][l] = fmaxf(acc, 0.f);
    }
    __syncthreads();

    if (l < H2N) {
        const float* W2 = Wh2 + (size_t)d * H1N * H2N;
        float acc = bh2[d * H2N + l];
        #pragma unroll
        for (int c = 0; c < H1N; ++c)
            acc = fmaf(y1[w][c], W2[c * H2N + l], acc);
        y2[w][l] = fmaxf(acc, 0.f);
    }
    __syncthreads();

    if (l < NWAY) {
        const float* W3 = Wh3 + (size_t)d * H2N * NWAY;
        float acc = bh3[d * NWAY + l];
        #pragma unroll
        for (int c = 0; c < H2N; ++c)
            acc = fmaf(y2[w][c], W3[c * NWAY + l], acc);
        out[(size_t)s * NWAY + l] = acc;
    }
}

// ---------------------------------------------------------------------------
extern "C" void kernel_launch(void* const* d_in, const int* in_sizes, int n_in,
                              void* d_out, int out_size, void* d_ws, size_t ws_size,
                              hipStream_t stream)
{
    const float* x_s   = (const float*)d_in[0];
    const float* x_p   = (const float*)d_in[1];
    const int*   tt    = (const int*)  d_in[2];
    const int*   dom   = (const int*)  d_in[3];
    const float* W_in  = (const float*)d_in[4];
    const float* b_in  = (const float*)d_in[5];
    const float* W_hid = (const float*)d_in[6];
    const float* b_hid = (const float*)d_in[7];
    const float* W_out = (const float*)d_in[8];
    const float* b_out = (const float*)d_in[9];
    const float* Wp    = (const float*)d_in[10];
    const float* bp    = (const float*)d_in[11];
    const float* gamma = (const float*)d_in[12];
    const float* beta  = (const float*)d_in[13];
    const float* Wh1   = (const float*)d_in[14];
    const float* bh1   = (const float*)d_in[15];
    const float* Wh2   = (const float*)d_in[16];
    const float* bh2   = (const float*)d_in[17];
    const float* Wh3   = (const float*)d_in[18];
    const float* bh3   = (const float*)d_in[19];
    float* out = (float*)d_out;

    // workspace layout (exactly 256 MiB):
    //  [0,   64M)  actA  bf16 [8192][4096]
    //  [64M, 128M) actB  bf16 [8192][4096]  /  X fp32 [8192][2048] (after GEMM5)
    //  [128M,224M) W_in^T bf16 [4096][12288] (transient, dead after GEMM1)
    //        then: W_out^T bf16 [1024][4096] @128M, Wp^T bf16 [1024][12288] @136M,
    //              BN buffers @160M
    //  [224M,256M) W_hid^T bf16 [4096][4096]
    char* w = (char*)d_ws;
    unsigned short* actA  = (unsigned short*)w;
    unsigned short* actB  = (unsigned short*)(w + 67108864);
    float*          X     = (float*)(w + 67108864);
    unsigned short* WinT  = (unsigned short*)(w + 134217728);
    unsigned short* WoutT = (unsigned short*)(w + 134217728);
    unsigned short* WpT   = (unsigned short*)(w + 142606336);
    float*          psum  = (float*)(w + 167772160);
    float*          pss   = psum + 32 * XW;
    float*          scale = pss  + 32 * XW;
    float*          shift = scale + XW;
    unsigned short* WhidT = (unsigned short*)(w + 234881024);

    const dim3 blk(256);

    // weight transposes (W_in^T + W_hid^T upfront; others after GEMM1 frees region)
    transpose_cvt<<<dim3(SUN/64,  FIN/64), blk, 0, stream>>>(W_in,  WinT,  FIN, SUN,  nullptr);
    transpose_cvt<<<dim3(SUN/64,  SUN/64), blk, 0, stream>>>(W_hid, WhidT, SUN, SUN,  nullptr);

    // GEMM1: x_s(fp32) @ W_in -> actA (relu)
    gemm_mfma<true,false,1><<<dim3(2048), blk, 0, stream>>>(
        x_s, WinT, b_in, actA, BQ, SUN, FIN, SUN, 0, nullptr, 0);

    transpose_cvt<<<dim3(HIDN/64, SUN/64), blk, 0, stream>>>(W_out, WoutT, SUN, HIDN, nullptr);
    transpose_cvt<<<dim3(HIDN/64, FIN/64), blk, 0, stream>>>(Wp,    WpT,   FIN, HIDN, dom);

    // GEMM2-5: hidden layers (relu), ping-pong actA/actB
    gemm_mfma<false,false,1><<<dim3(2048), blk, 0, stream>>>(
        actA, WhidT, b_hid, actB, BQ, SUN, SUN, SUN, 0, nullptr, 0);
    gemm_mfma<false,false,1><<<dim3(2048), blk, 0, stream>>>(
        actB, WhidT, b_hid, actA, BQ, SUN, SUN, SUN, 0, nullptr, 0);
    gemm_mfma<false,false,1><<<dim3(2048), blk, 0, stream>>>(
        actA, WhidT, b_hid, actB, BQ, SUN, SUN, SUN, 0, nullptr, 0);
    gemm_mfma<false,false,1><<<dim3(2048), blk, 0, stream>>>(
        actB, WhidT, b_hid, actA, BQ, SUN, SUN, SUN, 0, nullptr, 0);

    // GEMM6: h_shared (relu) -> X[:, 0:1024]  (fp32 out)
    gemm_mfma<false,true,1><<<dim3(512), blk, 0, stream>>>(
        actA, WoutT, b_out, X, BQ, HIDN, SUN, XW, 0, nullptr, 0);
    // GEMM7: x_p(fp32) @ Wp[dom] (leaky) -> X[:, 1024:2048]  (fp32 out)
    gemm_mfma<true,true,2><<<dim3(512), blk, 0, stream>>>(
        x_p, WpT, bp, X, BQ, HIDN, FIN, XW, HIDN, dom, HIDN);

    // BN + heads (fp32, proven in round 1)
    bn_stats_a<<<dim3(XW/256, 32), blk, 0, stream>>>(X, psum, pss);
    bn_stats_b<<<dim3(XW/256),     blk, 0, stream>>>(psum, pss, gamma, beta, scale, shift);
    head_kernel<<<dim3(BQ/4), blk, 0, stream>>>(X, scale, shift, tt,
                                                Wh1, bh1, Wh2, bh2, Wh3, bh3, out);
}

// Round 3
// 3297.739 us; speedup vs baseline: 9.4042x; 1.1542x over previous
//
#include <hip/hip_runtime.h>
#include <hip/hip_bf16.h>

// Problem constants
#define BQ    8192
#define FIN   12288
#define SUN   4096
#define HIDN  1024
#define XW    2048
#define H1N   28
#define H2N   14
#define NWAY  5
#define BN_EPS 1e-5f
#define LEAKS 0.001f

typedef __bf16 bf16x8 __attribute__((ext_vector_type(8)));
typedef float  f32x4  __attribute__((ext_vector_type(4)));
typedef unsigned short ushort8 __attribute__((ext_vector_type(8)));

__device__ __forceinline__ unsigned short f2bf(float f) {
    unsigned u = __float_as_uint(f);
    unsigned r = u + 0x7fffu + ((u >> 16) & 1u);   // RNE
    return (unsigned short)(r >> 16);
}

// Native packed convert path (v_cvt_pk_bf16_f32, RNE — bit-identical to f2bf)
__device__ __forceinline__ ushort8 cvt8(const float4 a, const float4 b) {
    union { __bf16 h[8]; ushort8 u; } r;
    r.h[0] = (__bf16)a.x; r.h[1] = (__bf16)a.y;
    r.h[2] = (__bf16)a.z; r.h[3] = (__bf16)a.w;
    r.h[4] = (__bf16)b.x; r.h[5] = (__bf16)b.y;
    r.h[6] = (__bf16)b.z; r.h[7] = (__bf16)b.w;
    return r.u;
}

#define TO_LDS(p) ((__attribute__((address_space(3))) void*)(p))
#define TO_GLB(p) ((const __attribute__((address_space(1))) void*)(p))

// ---------------------------------------------------------------------------
// Transpose + fp32->bf16 convert:  in[R][Cc] f32  ->  out[Cc][R] bf16
// ---------------------------------------------------------------------------
__global__ __launch_bounds__(256) void transpose_cvt(
    const float* __restrict__ in, unsigned short* __restrict__ out,
    int R, int Cc, const int* __restrict__ dom)
{
    if (dom) in += (size_t)(*dom) * (size_t)R * (size_t)Cc;
    __shared__ float tile[64][65];
    const int t  = threadIdx.x;
    const int tr = t >> 4;
    const int tc = t & 15;
    const int c0 = blockIdx.x * 64;
    const int r0 = blockIdx.y * 64;

    #pragma unroll
    for (int q = 0; q < 4; ++q) {
        const int r = r0 + tr + q * 16;
        const float4 v = *(const float4*)&in[(size_t)r * Cc + c0 + tc * 4];
        tile[tc*4+0][tr + q*16] = v.x;
        tile[tc*4+1][tr + q*16] = v.y;
        tile[tc*4+2][tr + q*16] = v.z;
        tile[tc*4+3][tr + q*16] = v.w;
    }
    __syncthreads();
    #pragma unroll
    for (int q = 0; q < 4; ++q) {
        const int c = c0 + tr + q * 16;
        ushort4 o;
        o.x = f2bf(tile[tr + q*16][tc*4+0]);
        o.y = f2bf(tile[tr + q*16][tc*4+1]);
        o.z = f2bf(tile[tr + q*16][tc*4+2]);
        o.w = f2bf(tile[tr + q*16][tc*4+3]);
        *(ushort4*)&out[(size_t)c * R + r0 + tc * 4] = o;
    }
}

// ---------------------------------------------------------------------------
// m97-structure bf16 MFMA GEMM (128x128, BK=32, 4 waves) — for GEMM1/6/7.
// ---------------------------------------------------------------------------
template<bool A_F32, bool OUT_F32, int ACT>
__global__ __launch_bounds__(256) void gemm_mfma(
    const void* __restrict__ Ap, const unsigned short* __restrict__ Bt,
    const float* __restrict__ bias, void* __restrict__ Cp,
    int M, int N, int K, int ldc, int cc0,
    const int* __restrict__ dom, int biasStride)
{
    __shared__ alignas(16) unsigned short As[128 * 32];
    __shared__ alignas(16) unsigned short Bs[128 * 32];

    const int nbx = N >> 7;
    int wg = blockIdx.x;
    const int nwg = gridDim.x;
    if ((nwg & 7) == 0) {
        const int cpx = nwg >> 3;
        wg = (wg & 7) * cpx + (wg >> 3);
    }
    const int bx = wg % nbx, by = wg / nbx;
    const int row0 = by << 7, col0 = bx << 7;

    const int t  = threadIdx.x;
    const int w  = t >> 6;
    const int l  = t & 63;
    const int wr = w >> 1, wc = w & 1;
    const int lr = l & 15, lk = l >> 4;

    f32x4 acc[4][4];
    #pragma unroll
    for (int i = 0; i < 4; ++i)
        #pragma unroll
        for (int j = 0; j < 4; ++j)
            acc[i][j] = (f32x4)(0.f);

    const int srow = l >> 2;
    const int skb  = (l & 3) * 16;
    const float* Af = (const float*)Ap;
    const unsigned short* Ab = (const unsigned short*)Ap;

    for (int k0 = 0; k0 < K; k0 += 32) {
        __syncthreads();

        #pragma unroll
        for (int c = 0; c < 2; ++c) {
            const int inst = w * 2 + c;
            const int row  = inst * 16 + srow;
            const char* src = (const char*)Bt +
                (((size_t)(col0 + row) * K + k0) * 2 + skb);
            char* dst = (char*)Bs + inst * 1024;
            __builtin_amdgcn_global_load_lds(TO_GLB(src), TO_LDS(dst), 16, 0, 0);
        }
        if (!A_F32) {
            #pragma unroll
            for (int c = 0; c < 2; ++c) {
                const int inst = w * 2 + c;
                const int row  = inst * 16 + srow;
                const char* src = (const char*)Ab +
                    (((size_t)(row0 + row) * K + k0) * 2 + skb);
                char* dst = (char*)As + inst * 1024;
                __builtin_amdgcn_global_load_lds(TO_GLB(src), TO_LDS(dst), 16, 0, 0);
            }
        } else {
            #pragma unroll
            for (int c = 0; c < 2; ++c) {
                const int ci  = t + 256 * c;
                const int row = ci >> 2;
                const int ko  = (ci & 3) * 8;
                const float* s = Af + (size_t)(row0 + row) * K + k0 + ko;
                const float4 v0 = *(const float4*)s;
                const float4 v1 = *(const float4*)(s + 4);
                *(ushort8*)&As[ci * 8] = cvt8(v0, v1);
            }
        }
        __syncthreads();

        bf16x8 af[4], bfv[4];
        #pragma unroll
        for (int i = 0; i < 4; ++i)
            af[i]  = *(const bf16x8*)&As[(wr*64 + i*16 + lr) * 32 + lk * 8];
        #pragma unroll
        for (int j = 0; j < 4; ++j)
            bfv[j] = *(const bf16x8*)&Bs[(wc*64 + j*16 + lr) * 32 + lk * 8];
        #pragma unroll
        for (int i = 0; i < 4; ++i)
            #pragma unroll
            for (int j = 0; j < 4; ++j)
                acc[i][j] = __builtin_amdgcn_mfma_f32_16x16x32_bf16(
                    af[i], bfv[j], acc[i][j], 0, 0, 0);
    }

    if (dom) bias += (*dom) * biasStride;
    const int colb = col0 + wc * 64 + lr;
    const int rowb = row0 + wr * 64 + lk * 4;
    float bj[4];
    #pragma unroll
    for (int j = 0; j < 4; ++j) bj[j] = bias[colb + j * 16];

    #pragma unroll
    for (int i = 0; i < 4; ++i) {
        #pragma unroll
        for (int r = 0; r < 4; ++r) {
            const size_t row = rowb + i * 16 + r;
            #pragma unroll
            for (int j = 0; j < 4; ++j) {
                float x = acc[i][j][r] + bj[j];
                if (ACT == 1)      x = fmaxf(x, 0.f);
                else if (ACT == 2) x = (x > 0.f) ? x : LEAKS * x;
                const size_t idx = row * (size_t)ldc + cc0 + colb + j * 16;
                if (OUT_F32) ((float*)Cp)[idx] = x;
                else         ((unsigned short*)Cp)[idx] = f2bf(x);
            }
        }
    }
}

// ---------------------------------------------------------------------------
// gemm256: 256x256 tile, BK=32, 8 waves (512 thr), TRIPLE-buffered LDS,
// distance-2 prefetch, counted vmcnt(4) + one raw barrier per K-tile.
// Fixed: relu, bf16 out, ldc=N. For the hidden GEMMs (bf16 A, Bt[N][K]).
// Race audit: tile t+1 staged during t-1; vmcnt(4) at end of tile t allows
// only t+2's 4 loads outstanding -> every thread drained its own t+1 loads
// before the barrier -> cross-wave LDS visibility guaranteed. Buf being
// staged (t+2)%3 was last read in tile t-1; those ds_reads delivered before
// t-1's MFMAs issued, hence before the t-1->t barrier. No aliasing races.
// ---------------------------------------------------------------------------
__global__ __launch_bounds__(512, 2) void gemm256(
    const unsigned short* __restrict__ A, const unsigned short* __restrict__ Bt,
    const float* __restrict__ bias, unsigned short* __restrict__ C,
    int M, int N, int K)
{
    __shared__ alignas(16) unsigned short lds[3][2][256 * 32];  // 96 KiB

    const int nbx = N >> 8;
    int wg = blockIdx.x;
    const int nwg = gridDim.x;
    if ((nwg & 7) == 0) {
        const int cpx = nwg >> 3;
        wg = (wg & 7) * cpx + (wg >> 3);
    }
    const int bx = wg % nbx, by = wg / nbx;
    const int row0 = by << 8, col0 = bx << 8;

    const int t  = threadIdx.x;
    const int w  = t >> 6, l = t & 63;
    const int wr = w >> 2, wc = w & 3;        // 2M x 4N waves, 128x64 each
    const int lr = l & 15, lk = l >> 4;
    const int srow = l >> 2, skel = (l & 3) * 8;

    f32x4 acc[8][4];
    #pragma unroll
    for (int i = 0; i < 8; ++i)
        #pragma unroll
        for (int j = 0; j < 4; ++j)
            acc[i][j] = (f32x4)(0.f);

    const int NT = K >> 5;

    #define STAGE256(tile_)  do {                                            \
        const int k0_  = (tile_) << 5;                                       \
        const int buf_ = (tile_) % 3;                                        \
        _Pragma("unroll")                                                    \
        for (int s_ = 0; s_ < 2; ++s_) {                                     \
            const int c_   = w * 2 + s_;                                     \
            const int row_ = c_ * 16 + srow;                                 \
            __builtin_amdgcn_global_load_lds(                                \
                TO_GLB(A + (size_t)(row0 + row_) * K + k0_ + skel),          \
                TO_LDS((char*)&lds[buf_][0][0] + c_ * 1024), 16, 0, 0);      \
            __builtin_amdgcn_global_load_lds(                                \
                TO_GLB(Bt + (size_t)(col0 + row_) * K + k0_ + skel),         \
                TO_LDS((char*)&lds[buf_][1][0] + c_ * 1024), 16, 0, 0);      \
        }                                                                    \
    } while (0)

    // prologue
    STAGE256(0);
    if (NT > 1) {
        STAGE256(1);
        asm volatile("s_waitcnt vmcnt(4)" ::: "memory");   // tile0 landed
    } else {
        asm volatile("s_waitcnt vmcnt(0)" ::: "memory");
    }
    __builtin_amdgcn_sched_barrier(0);
    __builtin_amdgcn_s_barrier();
    __builtin_amdgcn_sched_barrier(0);

    for (int tt = 0; tt < NT; ++tt) {
        const int buf = tt % 3;
        if (tt + 2 < NT) STAGE256(tt + 2);
        __builtin_amdgcn_sched_barrier(0);   // stage issues stay ahead of reads

        bf16x8 af[8], bfv[4];
        #pragma unroll
        for (int i = 0; i < 8; ++i)
            af[i]  = *(const bf16x8*)&lds[buf][0][(wr*128 + i*16 + lr) * 32 + lk * 8];
        #pragma unroll
        for (int j = 0; j < 4; ++j)
            bfv[j] = *(const bf16x8*)&lds[buf][1][(wc*64 + j*16 + lr) * 32 + lk * 8];

        #pragma unroll
        for (int j = 0; j < 4; ++j)
            #pragma unroll
            for (int i = 0; i < 8; ++i)
                acc[i][j] = __builtin_amdgcn_mfma_f32_16x16x32_bf16(
                    af[i], bfv[j], acc[i][j], 0, 0, 0);

        if (tt + 1 < NT) {
            if (tt + 2 < NT) asm volatile("s_waitcnt vmcnt(4)" ::: "memory");
            else             asm volatile("s_waitcnt vmcnt(0)" ::: "memory");
            __builtin_amdgcn_sched_barrier(0);
            __builtin_amdgcn_s_barrier();
            __builtin_amdgcn_sched_barrier(0);
        }
    }
    #undef STAGE256

    const int colb = col0 + wc * 64 + lr;
    const int rowb = row0 + wr * 128 + lk * 4;
    float bj[4];
    #pragma unroll
    for (int j = 0; j < 4; ++j) bj[j] = bias[colb + j * 16];

    #pragma unroll
    for (int i = 0; i < 8; ++i) {
        #pragma unroll
        for (int r = 0; r < 4; ++r) {
            const size_t row = rowb + i * 16 + r;
            #pragma unroll
            for (int j = 0; j < 4; ++j) {
                float x = fmaxf(acc[i][j][r] + bj[j], 0.f);
                C[row * (size_t)N + colb + j * 16] = f2bf(x);
            }
        }
    }
}

// ---------------------------------------------------------------------------
// BatchNorm stats + heads — unchanged (proven).
// ---------------------------------------------------------------------------
__global__ __launch_bounds__(256) void bn_stats_a(
    const float* __restrict__ X, float* __restrict__ psum, float* __restrict__ pss)
{
    const int c  = blockIdx.x * 256 + threadIdx.x;
    const int rb = blockIdx.y;
    float s = 0.f, ss = 0.f;
    const int r0 = rb * 256;
    for (int r = r0; r < r0 + 256; ++r) {
        float v = X[(size_t)r * XW + c];
        s += v; ss = fmaf(v, v, ss);
    }
    psum[rb * XW + c] = s;
    pss [rb * XW + c] = ss;
}

__global__ __launch_bounds__(256) void bn_stats_b(
    const float* __restrict__ psum, const float* __restrict__ pss,
    const float* __restrict__ gamma, const float* __restrict__ beta,
    float* __restrict__ scale, float* __restrict__ shift)
{
    const int c = blockIdx.x * 256 + threadIdx.x;
    float s = 0.f, ss = 0.f;
    for (int rb = 0; rb < 32; ++rb) { s += psum[rb * XW + c]; ss += pss[rb * XW + c]; }
    const float inv = 1.f / (float)BQ;
    const float mean = s * inv;
    const float var  = ss * inv - mean * mean;
    const float sc = gamma[c] * rsqrtf(var + BN_EPS);
    scale[c] = sc;
    shift[c] = beta[c] - mean * sc;
}

__global__ __launch_bounds__(256) void head_kernel(
    const float* __restrict__ X, const float* __restrict__ scale,
    const float* __restrict__ shift, const int* __restrict__ tt,
    const float* __restrict__ Wh1, const float* __restrict__ bh1,
    const float* __restrict__ Wh2, const float* __restrict__ bh2,
    const float* __restrict__ Wh3, const float* __restrict__ bh3,
    float* __restrict__ out)
{
    __shared__ float xs[4][XW];
    __shared__ float y1[4][H1N];
    __shared__ float y2[4][H2N + 2];

    const int t = threadIdx.x;
    const int w = t >> 6;
    const int l = t & 63;
    const int s = blockIdx.x * 4 + w;
    const int d = tt[s];

    #pragma unroll 4
    for (int i = 0; i < XW / 64; ++i) {
        const int c = i * 64 + l;
        xs[w][c] = fmaf(X[(size_t)s * XW + c], scale[c], shift[c]);
    }
    __syncthreads();

    if (l < H1N) {
        const float* W1 = Wh1 + (size_t)d * XW * H1N;
        float acc = bh1[d * H1N + l];
        #pragma unroll 8
        for (int c = 0; c < XW; ++c)
            acc = fmaf(xs[w][c], W1[c * H1N + l], acc);
        y1[w][l] = fmaxf(acc, 0.f);
    }
    __syncthreads();

    if (l < H2N) {
        const float* W2 = Wh2 + (size_t)d * H1N * H2N;
        float acc = bh2[d * H2N + l];
        #pragma unroll
        for (int c = 0; c < H1N; ++c)
            acc = fmaf(y1[w][c], W2[c * H2N + l], acc);
        y2[w][l] = fmaxf(acc, 0.f);
    }
    __syncthreads();

    if (l < NWAY) {
        const float* W3 = Wh3 + (size_t)d * H2N * NWAY;
        float acc = bh3[d * NWAY + l];
        #pragma unroll
        for (int c = 0; c < H2N; ++c)
            acc = fmaf(y2[w][c], W3[c * NWAY + l], acc);
        out[(size_t)s * NWAY + l] = acc;
    }
}

// ---------------------------------------------------------------------------
extern "C" void kernel_launch(void* const* d_in, const int* in_sizes, int n_in,
                              void* d_out, int out_size, void* d_ws, size_t ws_size,
                              hipStream_t stream)
{
    const float* x_s   = (const float*)d_in[0];
    const float* x_p   = (const float*)d_in[1];
    const int*   tt    = (const int*)  d_in[2];
    const int*   dom   = (const int*)  d_in[3];
    const float* W_in  = (const float*)d_in[4];
    const float* b_in  = (const float*)d_in[5];
    const float* W_hid = (const float*)d_in[6];
    const float* b_hid = (const float*)d_in[7];
    const float* W_out = (const float*)d_in[8];
    const float* b_out = (const float*)d_in[9];
    const float* Wp    = (const float*)d_in[10];
    const float* bp    = (const float*)d_in[11];
    const float* gamma = (const float*)d_in[12];
    const float* beta  = (const float*)d_in[13];
    const float* Wh1   = (const float*)d_in[14];
    const float* bh1   = (const float*)d_in[15];
    const float* Wh2   = (const float*)d_in[16];
    const float* bh2   = (const float*)d_in[17];
    const float* Wh3   = (const float*)d_in[18];
    const float* bh3   = (const float*)d_in[19];
    float* out = (float*)d_out;

    char* w = (char*)d_ws;
    unsigned short* actA  = (unsigned short*)w;
    unsigned short* actB  = (unsigned short*)(w + 67108864);
    float*          X     = (float*)(w + 67108864);
    unsigned short* WinT  = (unsigned short*)(w + 134217728);
    unsigned short* WoutT = (unsigned short*)(w + 134217728);
    unsigned short* WpT   = (unsigned short*)(w + 142606336);
    float*          psum  = (float*)(w + 167772160);
    float*          pss   = psum + 32 * XW;
    float*          scale = pss  + 32 * XW;
    float*          shift = scale + XW;
    unsigned short* WhidT = (unsigned short*)(w + 234881024);

    const dim3 blk(256);

    transpose_cvt<<<dim3(SUN/64,  FIN/64), blk, 0, stream>>>(W_in,  WinT,  FIN, SUN,  nullptr);
    transpose_cvt<<<dim3(SUN/64,  SUN/64), blk, 0, stream>>>(W_hid, WhidT, SUN, SUN,  nullptr);

    // GEMM1: x_s(fp32) @ W_in -> actA (relu)   [m97 structure, packed cvt]
    gemm_mfma<true,false,1><<<dim3(2048), blk, 0, stream>>>(
        x_s, WinT, b_in, actA, BQ, SUN, FIN, SUN, 0, nullptr, 0);

    transpose_cvt<<<dim3(HIDN/64, SUN/64), blk, 0, stream>>>(W_out, WoutT, SUN, HIDN, nullptr);
    transpose_cvt<<<dim3(HIDN/64, FIN/64), blk, 0, stream>>>(Wp,    WpT,   FIN, HIDN, dom);

    // GEMM2-5: hidden layers (relu) — new 256^2 triple-buffered kernel
    gemm256<<<dim3(512), dim3(512), 0, stream>>>(actA, WhidT, b_hid, actB, BQ, SUN, SUN);
    gemm256<<<dim3(512), dim3(512), 0, stream>>>(actB, WhidT, b_hid, actA, BQ, SUN, SUN);
    gemm256<<<dim3(512), dim3(512), 0, stream>>>(actA, WhidT, b_hid, actB, BQ, SUN, SUN);
    gemm256<<<dim3(512), dim3(512), 0, stream>>>(actB, WhidT, b_hid, actA, BQ, SUN, SUN);

    // GEMM6: h_shared (relu) -> X[:, 0:1024]  (fp32 out)
    gemm_mfma<false,true,1><<<dim3(512), blk, 0, stream>>>(
        actA, WoutT, b_out, X, BQ, HIDN, SUN, XW, 0, nullptr, 0);
    // GEMM7: x_p(fp32) @ Wp[dom] (leaky) -> X[:, 1024:2048]  (fp32 out)
    gemm_mfma<true,true,2><<<dim3(512), blk, 0, stream>>>(
        x_p, WpT, bp, X, BQ, HIDN, FIN, XW, HIDN, dom, HIDN);

    bn_stats_a<<<dim3(XW/256, 32), blk, 0, stream>>>(X, psum, pss);
    bn_stats_b<<<dim3(XW/256),     blk, 0, stream>>>(psum, pss, gamma, beta, scale, shift);
    head_kernel<<<dim3(BQ/4), blk, 0, stream>>>(X, scale, shift, tt,
                                                Wh1, bh1, Wh2, bh2, Wh3, bh3, out);
}

// Round 4
// 2706.503 us; speedup vs baseline: 11.4586x; 1.2185x over previous
//
#include <hip/hip_runtime.h>
#include <hip/hip_bf16.h>

// Problem constants
#define BQ    8192
#define FIN   12288
#define SUN   4096
#define HIDN  1024
#define XW    2048
#define H1N   28
#define H2N   14
#define NWAY  5
#define BN_EPS 1e-5f
#define LEAKS 0.001f

typedef __bf16 bf16x8 __attribute__((ext_vector_type(8)));
typedef float  f32x4  __attribute__((ext_vector_type(4)));
typedef unsigned short ushort8 __attribute__((ext_vector_type(8)));

__device__ __forceinline__ unsigned short f2bf(float f) {
    unsigned u = __float_as_uint(f);
    unsigned r = u + 0x7fffu + ((u >> 16) & 1u);   // RNE
    return (unsigned short)(r >> 16);
}

// Native packed convert (v_cvt_pk_bf16_f32, RNE — bit-identical to f2bf)
__device__ __forceinline__ ushort8 cvt8(const float4 a, const float4 b) {
    union { __bf16 h[8]; ushort8 u; } r;
    r.h[0] = (__bf16)a.x; r.h[1] = (__bf16)a.y;
    r.h[2] = (__bf16)a.z; r.h[3] = (__bf16)a.w;
    r.h[4] = (__bf16)b.x; r.h[5] = (__bf16)b.y;
    r.h[6] = (__bf16)b.z; r.h[7] = (__bf16)b.w;
    return r.u;
}

#define TO_LDS(p) ((__attribute__((address_space(3))) void*)(p))
#define TO_GLB(p) ((const __attribute__((address_space(1))) void*)(p))

// ---------------------------------------------------------------------------
// Bulk fp32 -> bf16 convert (grid-stride, 8 elems/thread/iter).
// ---------------------------------------------------------------------------
__global__ __launch_bounds__(256) void cvt_bf16(
    const float* __restrict__ in, unsigned short* __restrict__ out, long long n8)
{
    const long long idx = (long long)blockIdx.x * 256 + threadIdx.x;
    const long long stride = (long long)gridDim.x * 256;
    for (long long i = idx; i < n8; i += stride) {
        const float4 a = ((const float4*)in)[2 * i];
        const float4 b = ((const float4*)in)[2 * i + 1];
        ((ushort8*)out)[i] = cvt8(a, b);
    }
}

// ---------------------------------------------------------------------------
// Transpose + fp32->bf16 convert:  in[R][Cc] f32  ->  out[Cc][R] bf16
// ---------------------------------------------------------------------------
__global__ __launch_bounds__(256) void transpose_cvt(
    const float* __restrict__ in, unsigned short* __restrict__ out,
    int R, int Cc, const int* __restrict__ dom)
{
    if (dom) in += (size_t)(*dom) * (size_t)R * (size_t)Cc;
    __shared__ float tile[64][65];
    const int t  = threadIdx.x;
    const int tr = t >> 4;
    const int tc = t & 15;
    const int c0 = blockIdx.x * 64;
    const int r0 = blockIdx.y * 64;

    #pragma unroll
    for (int q = 0; q < 4; ++q) {
        const int r = r0 + tr + q * 16;
        const float4 v = *(const float4*)&in[(size_t)r * Cc + c0 + tc * 4];
        tile[tc*4+0][tr + q*16] = v.x;
        tile[tc*4+1][tr + q*16] = v.y;
        tile[tc*4+2][tr + q*16] = v.z;
        tile[tc*4+3][tr + q*16] = v.w;
    }
    __syncthreads();
    #pragma unroll
    for (int q = 0; q < 4; ++q) {
        const int c = c0 + tr + q * 16;
        ushort4 o;
        o.x = f2bf(tile[tr + q*16][tc*4+0]);
        o.y = f2bf(tile[tr + q*16][tc*4+1]);
        o.z = f2bf(tile[tr + q*16][tc*4+2]);
        o.w = f2bf(tile[tr + q*16][tc*4+3]);
        *(ushort4*)&out[(size_t)c * R + r0 + tc * 4] = o;
    }
}

// ---------------------------------------------------------------------------
// m97-structure bf16 MFMA GEMM (128x128, BK=32, 4 waves) — GEMM6/7 (+fallback).
// ---------------------------------------------------------------------------
template<bool A_F32, bool OUT_F32, int ACT>
__global__ __launch_bounds__(256) void gemm_mfma(
    const void* __restrict__ Ap, const unsigned short* __restrict__ Bt,
    const float* __restrict__ bias, void* __restrict__ Cp,
    int M, int N, int K, int ldc, int cc0,
    const int* __restrict__ dom, int biasStride)
{
    __shared__ alignas(16) unsigned short As[128 * 32];
    __shared__ alignas(16) unsigned short Bs[128 * 32];

    const int nbx = N >> 7;
    int wg = blockIdx.x;
    const int nwg = gridDim.x;
    if ((nwg & 7) == 0) {
        const int cpx = nwg >> 3;
        wg = (wg & 7) * cpx + (wg >> 3);
    }
    const int bx = wg % nbx, by = wg / nbx;
    const int row0 = by << 7, col0 = bx << 7;

    const int t  = threadIdx.x;
    const int w  = t >> 6;
    const int l  = t & 63;
    const int wr = w >> 1, wc = w & 1;
    const int lr = l & 15, lk = l >> 4;

    f32x4 acc[4][4];
    #pragma unroll
    for (int i = 0; i < 4; ++i)
        #pragma unroll
        for (int j = 0; j < 4; ++j)
            acc[i][j] = (f32x4)(0.f);

    const int srow = l >> 2;
    const int skb  = (l & 3) * 16;
    const float* Af = (const float*)Ap;
    const unsigned short* Ab = (const unsigned short*)Ap;

    for (int k0 = 0; k0 < K; k0 += 32) {
        __syncthreads();

        #pragma unroll
        for (int c = 0; c < 2; ++c) {
            const int inst = w * 2 + c;
            const int row  = inst * 16 + srow;
            const char* src = (const char*)Bt +
                (((size_t)(col0 + row) * K + k0) * 2 + skb);
            char* dst = (char*)Bs + inst * 1024;
            __builtin_amdgcn_global_load_lds(TO_GLB(src), TO_LDS(dst), 16, 0, 0);
        }
        if (!A_F32) {
            #pragma unroll
            for (int c = 0; c < 2; ++c) {
                const int inst = w * 2 + c;
                const int row  = inst * 16 + srow;
                const char* src = (const char*)Ab +
                    (((size_t)(row0 + row) * K + k0) * 2 + skb);
                char* dst = (char*)As + inst * 1024;
                __builtin_amdgcn_global_load_lds(TO_GLB(src), TO_LDS(dst), 16, 0, 0);
            }
        } else {
            #pragma unroll
            for (int c = 0; c < 2; ++c) {
                const int ci  = t + 256 * c;
                const int row = ci >> 2;
                const int ko  = (ci & 3) * 8;
                const float* s = Af + (size_t)(row0 + row) * K + k0 + ko;
                const float4 v0 = *(const float4*)s;
                const float4 v1 = *(const float4*)(s + 4);
                *(ushort8*)&As[ci * 8] = cvt8(v0, v1);
            }
        }
        __syncthreads();

        bf16x8 af[4], bfv[4];
        #pragma unroll
        for (int i = 0; i < 4; ++i)
            af[i]  = *(const bf16x8*)&As[(wr*64 + i*16 + lr) * 32 + lk * 8];
        #pragma unroll
        for (int j = 0; j < 4; ++j)
            bfv[j] = *(const bf16x8*)&Bs[(wc*64 + j*16 + lr) * 32 + lk * 8];
        #pragma unroll
        for (int i = 0; i < 4; ++i)
            #pragma unroll
            for (int j = 0; j < 4; ++j)
                acc[i][j] = __builtin_amdgcn_mfma_f32_16x16x32_bf16(
                    af[i], bfv[j], acc[i][j], 0, 0, 0);
    }

    if (dom) bias += (*dom) * biasStride;
    const int colb = col0 + wc * 64 + lr;
    const int rowb = row0 + wr * 64 + lk * 4;
    float bj[4];
    #pragma unroll
    for (int j = 0; j < 4; ++j) bj[j] = bias[colb + j * 16];

    #pragma unroll
    for (int i = 0; i < 4; ++i) {
        #pragma unroll
        for (int r = 0; r < 4; ++r) {
            const size_t row = rowb + i * 16 + r;
            #pragma unroll
            for (int j = 0; j < 4; ++j) {
                float x = acc[i][j][r] + bj[j];
                if (ACT == 1)      x = fmaxf(x, 0.f);
                else if (ACT == 2) x = (x > 0.f) ? x : LEAKS * x;
                const size_t idx = row * (size_t)ldc + cc0 + colb + j * 16;
                if (OUT_F32) ((float*)Cp)[idx] = x;
                else         ((unsigned short*)Cp)[idx] = f2bf(x);
            }
        }
    }
}

// ---------------------------------------------------------------------------
// gemm256: 256x256 tile, BK=32, 8 waves, triple-buffered LDS, distance-2
// prefetch, counted vmcnt(4). bf16 A/B via global_load_lds, relu, bf16 out.
// ---------------------------------------------------------------------------
__global__ __launch_bounds__(512, 2) void gemm256(
    const unsigned short* __restrict__ A, const unsigned short* __restrict__ Bt,
    const float* __restrict__ bias, unsigned short* __restrict__ C,
    int M, int N, int K)
{
    __shared__ alignas(16) unsigned short lds[3][2][256 * 32];  // 96 KiB

    const int nbx = N >> 8;
    int wg = blockIdx.x;
    const int nwg = gridDim.x;
    if ((nwg & 7) == 0) {
        const int cpx = nwg >> 3;
        wg = (wg & 7) * cpx + (wg >> 3);
    }
    const int bx = wg % nbx, by = wg / nbx;
    const int row0 = by << 8, col0 = bx << 8;

    const int t  = threadIdx.x;
    const int w  = t >> 6, l = t & 63;
    const int wr = w >> 2, wc = w & 3;
    const int lr = l & 15, lk = l >> 4;
    const int srow = l >> 2, skel = (l & 3) * 8;

    f32x4 acc[8][4];
    #pragma unroll
    for (int i = 0; i < 8; ++i)
        #pragma unroll
        for (int j = 0; j < 4; ++j)
            acc[i][j] = (f32x4)(0.f);

    const int NT = K >> 5;

    #define STAGE256(tile_)  do {                                            \
        const int k0_  = (tile_) << 5;                                       \
        const int buf_ = (tile_) % 3;                                        \
        _Pragma("unroll")                                                    \
        for (int s_ = 0; s_ < 2; ++s_) {                                     \
            const int c_   = w * 2 + s_;                                     \
            const int row_ = c_ * 16 + srow;                                 \
            __builtin_amdgcn_global_load_lds(                                \
                TO_GLB(A + (size_t)(row0 + row_) * K + k0_ + skel),          \
                TO_LDS((char*)&lds[buf_][0][0] + c_ * 1024), 16, 0, 0);      \
            __builtin_amdgcn_global_load_lds(                                \
                TO_GLB(Bt + (size_t)(col0 + row_) * K + k0_ + skel),         \
                TO_LDS((char*)&lds[buf_][1][0] + c_ * 1024), 16, 0, 0);      \
        }                                                                    \
    } while (0)

    STAGE256(0);
    if (NT > 1) {
        STAGE256(1);
        asm volatile("s_waitcnt vmcnt(4)" ::: "memory");
    } else {
        asm volatile("s_waitcnt vmcnt(0)" ::: "memory");
    }
    __builtin_amdgcn_sched_barrier(0);
    __builtin_amdgcn_s_barrier();
    __builtin_amdgcn_sched_barrier(0);

    for (int tt = 0; tt < NT; ++tt) {
        const int buf = tt % 3;
        if (tt + 2 < NT) STAGE256(tt + 2);
        __builtin_amdgcn_sched_barrier(0);

        bf16x8 af[8], bfv[4];
        #pragma unroll
        for (int i = 0; i < 8; ++i)
            af[i]  = *(const bf16x8*)&lds[buf][0][(wr*128 + i*16 + lr) * 32 + lk * 8];
        #pragma unroll
        for (int j = 0; j < 4; ++j)
            bfv[j] = *(const bf16x8*)&lds[buf][1][(wc*64 + j*16 + lr) * 32 + lk * 8];

        #pragma unroll
        for (int j = 0; j < 4; ++j)
            #pragma unroll
            for (int i = 0; i < 8; ++i)
                acc[i][j] = __builtin_amdgcn_mfma_f32_16x16x32_bf16(
                    af[i], bfv[j], acc[i][j], 0, 0, 0);

        if (tt + 1 < NT) {
            if (tt + 2 < NT) asm volatile("s_waitcnt vmcnt(4)" ::: "memory");
            else             asm volatile("s_waitcnt vmcnt(0)" ::: "memory");
            __builtin_amdgcn_sched_barrier(0);
            __builtin_amdgcn_s_barrier();
            __builtin_amdgcn_sched_barrier(0);
        }
    }
    #undef STAGE256

    const int colb = col0 + wc * 64 + lr;
    const int rowb = row0 + wr * 128 + lk * 4;
    float bj[4];
    #pragma unroll
    for (int j = 0; j < 4; ++j) bj[j] = bias[colb + j * 16];

    #pragma unroll
    for (int i = 0; i < 8; ++i) {
        #pragma unroll
        for (int r = 0; r < 4; ++r) {
            const size_t row = rowb + i * 16 + r;
            #pragma unroll
            for (int j = 0; j < 4; ++j) {
                float x = fmaxf(acc[i][j][r] + bj[j], 0.f);
                C[row * (size_t)N + colb + j * 16] = f2bf(x);
            }
        }
    }
}

// ---------------------------------------------------------------------------
// BatchNorm stats + heads — unchanged (proven).
// ---------------------------------------------------------------------------
__global__ __launch_bounds__(256) void bn_stats_a(
    const float* __restrict__ X, float* __restrict__ psum, float* __restrict__ pss)
{
    const int c  = blockIdx.x * 256 + threadIdx.x;
    const int rb = blockIdx.y;
    float s = 0.f, ss = 0.f;
    const int r0 = rb * 256;
    for (int r = r0; r < r0 + 256; ++r) {
        float v = X[(size_t)r * XW + c];
        s += v; ss = fmaf(v, v, ss);
    }
    psum[rb * XW + c] = s;
    pss [rb * XW + c] = ss;
}

__global__ __launch_bounds__(256) void bn_stats_b(
    const float* __restrict__ psum, const float* __restrict__ pss,
    const float* __restrict__ gamma, const float* __restrict__ beta,
    float* __restrict__ scale, float* __restrict__ shift)
{
    const int c = blockIdx.x * 256 + threadIdx.x;
    float s = 0.f, ss = 0.f;
    for (int rb = 0; rb < 32; ++rb) { s += psum[rb * XW + c]; ss += pss[rb * XW + c]; }
    const float inv = 1.f / (float)BQ;
    const float mean = s * inv;
    const float var  = ss * inv - mean * mean;
    const float sc = gamma[c] * rsqrtf(var + BN_EPS);
    scale[c] = sc;
    shift[c] = beta[c] - mean * sc;
}

__global__ __launch_bounds__(256) void head_kernel(
    const float* __restrict__ X, const float* __restrict__ scale,
    const float* __restrict__ shift, const int* __restrict__ tt,
    const float* __restrict__ Wh1, const float* __restrict__ bh1,
    const float* __restrict__ Wh2, const float* __restrict__ bh2,
    const float* __restrict__ Wh3, const float* __restrict__ bh3,
    float* __restrict__ out)
{
    __shared__ float xs[4][XW];
    __shared__ float y1[4][H1N];
    __shared__ float y2[4][H2N + 2];

    const int t = threadIdx.x;
    const int w = t >> 6;
    const int l = t & 63;
    const int s = blockIdx.x * 4 + w;
    const int d = tt[s];

    #pragma unroll 4
    for (int i = 0; i < XW / 64; ++i) {
        const int c = i * 64 + l;
        xs[w][c] = fmaf(X[(size_t)s * XW + c], scale[c], shift[c]);
    }
    __syncthreads();

    if (l < H1N) {
        const float* W1 = Wh1 + (size_t)d * XW * H1N;
        float acc = bh1[d * H1N + l];
        #pragma unroll 8
        for (int c = 0; c < XW; ++c)
            acc = fmaf(xs[w][c], W1[c * H1N + l], acc);
        y1[w][l] = fmaxf(acc, 0.f);
    }
    __syncthreads();

    if (l < H2N) {
        const float* W2 = Wh2 + (size_t)d * H1N * H2N;
        float acc = bh2[d * H2N + l];
        #pragma unroll
        for (int c = 0; c < H1N; ++c)
            acc = fmaf(y1[w][c], W2[c * H2N + l], acc);
        y2[w][l] = fmaxf(acc, 0.f);
    }
    __syncthreads();

    if (l < NWAY) {
        const float* W3 = Wh3 + (size_t)d * H2N * NWAY;
        float acc = bh3[d * NWAY + l];
        #pragma unroll
        for (int c = 0; c < H2N; ++c)
            acc = fmaf(y2[w][c], W3[c * NWAY + l], acc);
        out[(size_t)s * NWAY + l] = acc;
    }
}

// ---------------------------------------------------------------------------
extern "C" void kernel_launch(void* const* d_in, const int* in_sizes, int n_in,
                              void* d_out, int out_size, void* d_ws, size_t ws_size,
                              hipStream_t stream)
{
    const float* x_s   = (const float*)d_in[0];
    const float* x_p   = (const float*)d_in[1];
    const int*   tt    = (const int*)  d_in[2];
    const int*   dom   = (const int*)  d_in[3];
    const float* W_in  = (const float*)d_in[4];
    const float* b_in  = (const float*)d_in[5];
    const float* W_hid = (const float*)d_in[6];
    const float* b_hid = (const float*)d_in[7];
    const float* W_out = (const float*)d_in[8];
    const float* b_out = (const float*)d_in[9];
    const float* Wp    = (const float*)d_in[10];
    const float* bp    = (const float*)d_in[11];
    const float* gamma = (const float*)d_in[12];
    const float* beta  = (const float*)d_in[13];
    const float* Wh1   = (const float*)d_in[14];
    const float* bh1   = (const float*)d_in[15];
    const float* Wh2   = (const float*)d_in[16];
    const float* bh2   = (const float*)d_in[17];
    const float* Wh3   = (const float*)d_in[18];
    const float* bh3   = (const float*)d_in[19];
    float* out = (float*)d_out;

    const dim3 blk(256);
    char* w = (char*)d_ws;

    // Fast path needs: xb 192M | WT region 96M | actA 64M | actB/X 64M |
    //                  WhidT 32M | BN ~1M  = 449 MiB
    const size_t FAST_NEED = 470810624ull;

    if (ws_size >= FAST_NEED) {
        unsigned short* xb    = (unsigned short*)w;                    // 192M
        unsigned short* WinT  = (unsigned short*)(w + 201326592);      // 96M region
        unsigned short* WoutT = (unsigned short*)(w + 201326592);      //  8M
        unsigned short* WpT   = (unsigned short*)(w + 209715200);      // 24M
        unsigned short* actA  = (unsigned short*)(w + 301989888);      // 64M
        unsigned short* actB  = (unsigned short*)(w + 369098752);      // 64M
        float*          X     = (float*)(w + 369098752);               // aliases actB
        unsigned short* WhidT = (unsigned short*)(w + 436207616);      // 32M
        float*          psum  = (float*)(w + 469762048);
        float*          pss   = psum + 32 * XW;
        float*          scale = pss  + 32 * XW;
        float*          shift = scale + XW;

        // x_s -> bf16 (L3-resident 192M), weight transposes
        cvt_bf16<<<dim3(2048), blk, 0, stream>>>(x_s, xb, (long long)BQ * FIN / 8);
        transpose_cvt<<<dim3(SUN/64,  FIN/64), blk, 0, stream>>>(W_in,  WinT,  FIN, SUN,  nullptr);
        transpose_cvt<<<dim3(SUN/64,  SUN/64), blk, 0, stream>>>(W_hid, WhidT, SUN, SUN,  nullptr);

        // GEMM1 via gemm256 (pure bf16 pipeline)
        gemm256<<<dim3(512), dim3(512), 0, stream>>>(xb, WinT, b_in, actA, BQ, SUN, FIN);

        // WinT dead -> WoutT/WpT; xb dead -> x_p bf16
        transpose_cvt<<<dim3(HIDN/64, SUN/64), blk, 0, stream>>>(W_out, WoutT, SUN, HIDN, nullptr);
        transpose_cvt<<<dim3(HIDN/64, FIN/64), blk, 0, stream>>>(Wp,    WpT,   FIN, HIDN, dom);
        cvt_bf16<<<dim3(2048), blk, 0, stream>>>(x_p, xb, (long long)BQ * FIN / 8);

        // hidden layers
        gemm256<<<dim3(512), dim3(512), 0, stream>>>(actA, WhidT, b_hid, actB, BQ, SUN, SUN);
        gemm256<<<dim3(512), dim3(512), 0, stream>>>(actB, WhidT, b_hid, actA, BQ, SUN, SUN);
        gemm256<<<dim3(512), dim3(512), 0, stream>>>(actA, WhidT, b_hid, actB, BQ, SUN, SUN);
        gemm256<<<dim3(512), dim3(512), 0, stream>>>(actB, WhidT, b_hid, actA, BQ, SUN, SUN);

        // GEMM6 / GEMM7 (bf16 A via global_load_lds)
        gemm_mfma<false,true,1><<<dim3(512), blk, 0, stream>>>(
            actA, WoutT, b_out, X, BQ, HIDN, SUN, XW, 0, nullptr, 0);
        gemm_mfma<false,true,2><<<dim3(512), blk, 0, stream>>>(
            xb, WpT, bp, X, BQ, HIDN, FIN, XW, HIDN, dom, HIDN);

        bn_stats_a<<<dim3(XW/256, 32), blk, 0, stream>>>(X, psum, pss);
        bn_stats_b<<<dim3(XW/256),     blk, 0, stream>>>(psum, pss, gamma, beta, scale, shift);
        head_kernel<<<dim3(BQ/4), blk, 0, stream>>>(X, scale, shift, tt,
                                                    Wh1, bh1, Wh2, bh2, Wh3, bh3, out);
        return;
    }

    // ---------------- fallback: proven round-3 path (256 MiB) ----------------
    unsigned short* actA  = (unsigned short*)w;
    unsigned short* actB  = (unsigned short*)(w + 67108864);
    float*          X     = (float*)(w + 67108864);
    unsigned short* WinT  = (unsigned short*)(w + 134217728);
    unsigned short* WoutT = (unsigned short*)(w + 134217728);
    unsigned short* WpT   = (unsigned short*)(w + 142606336);
    float*          psum  = (float*)(w + 167772160);
    float*          pss   = psum + 32 * XW;
    float*          scale = pss  + 32 * XW;
    float*          shift = scale + XW;
    unsigned short* WhidT = (unsigned short*)(w + 234881024);

    transpose_cvt<<<dim3(SUN/64,  FIN/64), blk, 0, stream>>>(W_in,  WinT,  FIN, SUN,  nullptr);
    transpose_cvt<<<dim3(SUN/64,  SUN/64), blk, 0, stream>>>(W_hid, WhidT, SUN, SUN,  nullptr);

    gemm_mfma<true,false,1><<<dim3(2048), blk, 0, stream>>>(
        x_s, WinT, b_in, actA, BQ, SUN, FIN, SUN, 0, nullptr, 0);

    transpose_cvt<<<dim3(HIDN/64, SUN/64), blk, 0, stream>>>(W_out, WoutT, SUN, HIDN, nullptr);
    transpose_cvt<<<dim3(HIDN/64, FIN/64), blk, 0, stream>>>(Wp,    WpT,   FIN, HIDN, dom);

    gemm256<<<dim3(512), dim3(512), 0, stream>>>(actA, WhidT, b_hid, actB, BQ, SUN, SUN);
    gemm256<<<dim3(512), dim3(512), 0, stream>>>(actB, WhidT, b_hid, actA, BQ, SUN, SUN);
    gemm256<<<dim3(512), dim3(512), 0, stream>>>(actA, WhidT, b_hid, actB, BQ, SUN, SUN);
    gemm256<<<dim3(512), dim3(512), 0, stream>>>(actB, WhidT, b_hid, actA, BQ, SUN, SUN);

    gemm_mfma<false,true,1><<<dim3(512), blk, 0, stream>>>(
        actA, WoutT, b_out, X, BQ, HIDN, SUN, XW, 0, nullptr, 0);
    gemm_mfma<true,true,2><<<dim3(512), blk, 0, stream>>>(
        x_p, WpT, bp, X, BQ, HIDN, FIN, XW, HIDN, dom, HIDN);

    bn_stats_a<<<dim3(XW/256, 32), blk, 0, stream>>>(X, psum, pss);
    bn_stats_b<<<dim3(XW/256),     blk, 0, stream>>>(psum, pss, gamma, beta, scale, shift);
    head_kernel<<<dim3(BQ/4), blk, 0, stream>>>(X, scale, shift, tt,
                                                Wh1, bh1, Wh2, bh2, Wh3, bh3, out);
}

// Round 5
// 2619.499 us; speedup vs baseline: 11.8392x; 1.0332x over previous
//
#include <hip/hip_runtime.h>
#include <hip/hip_bf16.h>

// Problem constants
#define BQ    8192
#define FIN   12288
#define SUN   4096
#define HIDN  1024
#define XW    2048
#define H1N   28
#define H2N   14
#define NWAY  5
#define BN_EPS 1e-5f
#define LEAKS 0.001f

typedef __bf16 bf16x8 __attribute__((ext_vector_type(8)));
typedef float  f32x4  __attribute__((ext_vector_type(4)));
typedef unsigned short ushort8 __attribute__((ext_vector_type(8)));

__device__ __forceinline__ unsigned short f2bf(float f) {
    unsigned u = __float_as_uint(f);
    unsigned r = u + 0x7fffu + ((u >> 16) & 1u);   // RNE
    return (unsigned short)(r >> 16);
}

// Native packed convert (v_cvt_pk_bf16_f32, RNE — bit-identical to f2bf)
__device__ __forceinline__ ushort8 cvt8(const float4 a, const float4 b) {
    union { __bf16 h[8]; ushort8 u; } r;
    r.h[0] = (__bf16)a.x; r.h[1] = (__bf16)a.y;
    r.h[2] = (__bf16)a.z; r.h[3] = (__bf16)a.w;
    r.h[4] = (__bf16)b.x; r.h[5] = (__bf16)b.y;
    r.h[6] = (__bf16)b.z; r.h[7] = (__bf16)b.w;
    return r.u;
}

#define TO_LDS(p) ((__attribute__((address_space(3))) void*)(p))
#define TO_GLB(p) ((const __attribute__((address_space(1))) void*)(p))

// LDS tile layout: row-major [row][32] bf16 (64 B rows). T2 XOR-swizzle:
// logical k-granule lk (8 elems) of row r lives at phys granule lk ^ ((r>>1)&3).
// Staged via gload_lds with LINEAR dest + pre-swizzled GLOBAL source (rule #21):
// lane l's 16B lands in row (l>>2) of its chunk at phys granule (l&3), so the
// source k-granule is (l&3) ^ ((l>>3)&3).  Reads XOR with (lr>>1)&3.

// ---------------------------------------------------------------------------
// Bulk fp32 -> bf16 convert (grid-stride, 8 elems/thread/iter).
// ---------------------------------------------------------------------------
__global__ __launch_bounds__(256) void cvt_bf16(
    const float* __restrict__ in, unsigned short* __restrict__ out, long long n8)
{
    const long long idx = (long long)blockIdx.x * 256 + threadIdx.x;
    const long long stride = (long long)gridDim.x * 256;
    for (long long i = idx; i < n8; i += stride) {
        const float4 a = ((const float4*)in)[2 * i];
        const float4 b = ((const float4*)in)[2 * i + 1];
        ((ushort8*)out)[i] = cvt8(a, b);
    }
}

// ---------------------------------------------------------------------------
// Transpose + fp32->bf16 convert:  in[R][Cc] f32  ->  out[Cc][R] bf16
// ---------------------------------------------------------------------------
__global__ __launch_bounds__(256) void transpose_cvt(
    const float* __restrict__ in, unsigned short* __restrict__ out,
    int R, int Cc, const int* __restrict__ dom)
{
    if (dom) in += (size_t)(*dom) * (size_t)R * (size_t)Cc;
    __shared__ float tile[64][65];
    const int t  = threadIdx.x;
    const int tr = t >> 4;
    const int tc = t & 15;
    const int c0 = blockIdx.x * 64;
    const int r0 = blockIdx.y * 64;

    #pragma unroll
    for (int q = 0; q < 4; ++q) {
        const int r = r0 + tr + q * 16;
        const float4 v = *(const float4*)&in[(size_t)r * Cc + c0 + tc * 4];
        tile[tc*4+0][tr + q*16] = v.x;
        tile[tc*4+1][tr + q*16] = v.y;
        tile[tc*4+2][tr + q*16] = v.z;
        tile[tc*4+3][tr + q*16] = v.w;
    }
    __syncthreads();
    #pragma unroll
    for (int q = 0; q < 4; ++q) {
        const int c = c0 + tr + q * 16;
        ushort4 o;
        o.x = f2bf(tile[tr + q*16][tc*4+0]);
        o.y = f2bf(tile[tr + q*16][tc*4+1]);
        o.z = f2bf(tile[tr + q*16][tc*4+2]);
        o.w = f2bf(tile[tr + q*16][tc*4+3]);
        *(ushort4*)&out[(size_t)c * R + r0 + tc * 4] = o;
    }
}

// ---------------------------------------------------------------------------
// m97-structure bf16 MFMA GEMM (128x128, BK=32, 4 waves) — GEMM6/7 (+fallback).
// Now with T2 swizzle (source-side + read-side XOR).
// ---------------------------------------------------------------------------
template<bool A_F32, bool OUT_F32, int ACT>
__global__ __launch_bounds__(256) void gemm_mfma(
    const void* __restrict__ Ap, const unsigned short* __restrict__ Bt,
    const float* __restrict__ bias, void* __restrict__ Cp,
    int M, int N, int K, int ldc, int cc0,
    const int* __restrict__ dom, int biasStride)
{
    __shared__ alignas(16) unsigned short As[128 * 32];
    __shared__ alignas(16) unsigned short Bs[128 * 32];

    const int nbx = N >> 7;
    int wg = blockIdx.x;
    const int nwg = gridDim.x;
    if ((nwg & 7) == 0) {
        const int cpx = nwg >> 3;
        wg = (wg & 7) * cpx + (wg >> 3);
    }
    const int bx = wg % nbx, by = wg / nbx;
    const int row0 = by << 7, col0 = bx << 7;

    const int t  = threadIdx.x;
    const int w  = t >> 6;
    const int l  = t & 63;
    const int wr = w >> 1, wc = w & 1;
    const int lr = l & 15, lk = l >> 4;
    const int rsw = (lr >> 1) & 3;            // read-side swizzle

    f32x4 acc[4][4];
    #pragma unroll
    for (int i = 0; i < 4; ++i)
        #pragma unroll
        for (int j = 0; j < 4; ++j)
            acc[i][j] = (f32x4)(0.f);

    const int srow = l >> 2;
    const int skb  = (((l & 3) ^ ((l >> 3) & 3)) * 16);   // swizzled source bytes
    const float* Af = (const float*)Ap;
    const unsigned short* Ab = (const unsigned short*)Ap;

    for (int k0 = 0; k0 < K; k0 += 32) {
        __syncthreads();

        #pragma unroll
        for (int c = 0; c < 2; ++c) {
            const int inst = w * 2 + c;
            const int row  = inst * 16 + srow;
            const char* src = (const char*)Bt +
                (((size_t)(col0 + row) * K + k0) * 2 + skb);
            char* dst = (char*)Bs + inst * 1024;
            __builtin_amdgcn_global_load_lds(TO_GLB(src), TO_LDS(dst), 16, 0, 0);
        }
        if (!A_F32) {
            #pragma unroll
            for (int c = 0; c < 2; ++c) {
                const int inst = w * 2 + c;
                const int row  = inst * 16 + srow;
                const char* src = (const char*)Ab +
                    (((size_t)(row0 + row) * K + k0) * 2 + skb);
                char* dst = (char*)As + inst * 1024;
                __builtin_amdgcn_global_load_lds(TO_GLB(src), TO_LDS(dst), 16, 0, 0);
            }
        } else {
            #pragma unroll
            for (int c = 0; c < 2; ++c) {
                const int ci  = t + 256 * c;
                const int row = ci >> 2;
                const int ko  = (((ci & 3) ^ ((ci >> 3) & 3)) * 8);  // swizzled
                const float* s = Af + (size_t)(row0 + row) * K + k0 + ko;
                const float4 v0 = *(const float4*)s;
                const float4 v1 = *(const float4*)(s + 4);
                *(ushort8*)&As[ci * 8] = cvt8(v0, v1);
            }
        }
        __syncthreads();

        bf16x8 af[4], bfv[4];
        #pragma unroll
        for (int i = 0; i < 4; ++i)
            af[i]  = *(const bf16x8*)&As[(wr*64 + i*16 + lr) * 32 + (lk ^ rsw) * 8];
        #pragma unroll
        for (int j = 0; j < 4; ++j)
            bfv[j] = *(const bf16x8*)&Bs[(wc*64 + j*16 + lr) * 32 + (lk ^ rsw) * 8];
        #pragma unroll
        for (int i = 0; i < 4; ++i)
            #pragma unroll
            for (int j = 0; j < 4; ++j)
                acc[i][j] = __builtin_amdgcn_mfma_f32_16x16x32_bf16(
                    af[i], bfv[j], acc[i][j], 0, 0, 0);
    }

    if (dom) bias += (*dom) * biasStride;
    const int colb = col0 + wc * 64 + lr;
    const int rowb = row0 + wr * 64 + lk * 4;
    float bj[4];
    #pragma unroll
    for (int j = 0; j < 4; ++j) bj[j] = bias[colb + j * 16];

    #pragma unroll
    for (int i = 0; i < 4; ++i) {
        #pragma unroll
        for (int r = 0; r < 4; ++r) {
            const size_t row = rowb + i * 16 + r;
            #pragma unroll
            for (int j = 0; j < 4; ++j) {
                float x = acc[i][j][r] + bj[j];
                if (ACT == 1)      x = fmaxf(x, 0.f);
                else if (ACT == 2) x = (x > 0.f) ? x : LEAKS * x;
                const size_t idx = row * (size_t)ldc + cc0 + colb + j * 16;
                if (OUT_F32) ((float*)Cp)[idx] = x;
                else         ((unsigned short*)Cp)[idx] = f2bf(x);
            }
        }
    }
}

// ---------------------------------------------------------------------------
// gemm256: 256x256 tile, BK=32, 8 waves, triple-buffered LDS, distance-2
// prefetch, counted vmcnt(4), T2 swizzle. bf16 in/out, relu.
// ---------------------------------------------------------------------------
__global__ __launch_bounds__(512, 2) void gemm256(
    const unsigned short* __restrict__ A, const unsigned short* __restrict__ Bt,
    const float* __restrict__ bias, unsigned short* __restrict__ C,
    int M, int N, int K)
{
    __shared__ alignas(16) unsigned short lds[3][2][256 * 32];  // 96 KiB

    const int nbx = N >> 8;
    int wg = blockIdx.x;
    const int nwg = gridDim.x;
    if ((nwg & 7) == 0) {
        const int cpx = nwg >> 3;
        wg = (wg & 7) * cpx + (wg >> 3);
    }
    const int bx = wg % nbx, by = wg / nbx;
    const int row0 = by << 8, col0 = bx << 8;

    const int t  = threadIdx.x;
    const int w  = t >> 6, l = t & 63;
    const int wr = w >> 2, wc = w & 3;
    const int lr = l & 15, lk = l >> 4;
    const int rsw = (lr >> 1) & 3;                         // read swizzle
    const int srow = l >> 2;
    const int skel = ((l & 3) ^ ((l >> 3) & 3)) * 8;       // swizzled src elems

    f32x4 acc[8][4];
    #pragma unroll
    for (int i = 0; i < 8; ++i)
        #pragma unroll
        for (int j = 0; j < 4; ++j)
            acc[i][j] = (f32x4)(0.f);

    const int NT = K >> 5;

    #define STAGE256(tile_)  do {                                            \
        const int k0_  = (tile_) << 5;                                       \
        const int buf_ = (tile_) % 3;                                        \
        _Pragma("unroll")                                                    \
        for (int s_ = 0; s_ < 2; ++s_) {                                     \
            const int c_   = w * 2 + s_;                                     \
            const int row_ = c_ * 16 + srow;                                 \
            __builtin_amdgcn_global_load_lds(                                \
                TO_GLB(A + (size_t)(row0 + row_) * K + k0_ + skel),          \
                TO_LDS((char*)&lds[buf_][0][0] + c_ * 1024), 16, 0, 0);      \
            __builtin_amdgcn_global_load_lds(                                \
                TO_GLB(Bt + (size_t)(col0 + row_) * K + k0_ + skel),         \
                TO_LDS((char*)&lds[buf_][1][0] + c_ * 1024), 16, 0, 0);      \
        }                                                                    \
    } while (0)

    STAGE256(0);
    if (NT > 1) {
        STAGE256(1);
        asm volatile("s_waitcnt vmcnt(4)" ::: "memory");
    } else {
        asm volatile("s_waitcnt vmcnt(0)" ::: "memory");
    }
    __builtin_amdgcn_sched_barrier(0);
    __builtin_amdgcn_s_barrier();
    __builtin_amdgcn_sched_barrier(0);

    for (int tt = 0; tt < NT; ++tt) {
        const int buf = tt % 3;
        if (tt + 2 < NT) STAGE256(tt + 2);
        __builtin_amdgcn_sched_barrier(0);

        bf16x8 af[8], bfv[4];
        #pragma unroll
        for (int i = 0; i < 8; ++i)
            af[i]  = *(const bf16x8*)&lds[buf][0][(wr*128 + i*16 + lr) * 32 + (lk ^ rsw) * 8];
        #pragma unroll
        for (int j = 0; j < 4; ++j)
            bfv[j] = *(const bf16x8*)&lds[buf][1][(wc*64 + j*16 + lr) * 32 + (lk ^ rsw) * 8];

        #pragma unroll
        for (int j = 0; j < 4; ++j)
            #pragma unroll
            for (int i = 0; i < 8; ++i)
                acc[i][j] = __builtin_amdgcn_mfma_f32_16x16x32_bf16(
                    af[i], bfv[j], acc[i][j], 0, 0, 0);

        if (tt + 1 < NT) {
            if (tt + 2 < NT) asm volatile("s_waitcnt vmcnt(4)" ::: "memory");
            else             asm volatile("s_waitcnt vmcnt(0)" ::: "memory");
            __builtin_amdgcn_sched_barrier(0);
            __builtin_amdgcn_s_barrier();
            __builtin_amdgcn_sched_barrier(0);
        }
    }
    #undef STAGE256

    const int colb = col0 + wc * 64 + lr;
    const int rowb = row0 + wr * 128 + lk * 4;
    float bj[4];
    #pragma unroll
    for (int j = 0; j < 4; ++j) bj[j] = bias[colb + j * 16];

    #pragma unroll
    for (int i = 0; i < 8; ++i) {
        #pragma unroll
        for (int r = 0; r < 4; ++r) {
            const size_t row = rowb + i * 16 + r;
            #pragma unroll
            for (int j = 0; j < 4; ++j) {
                float x = fmaxf(acc[i][j][r] + bj[j], 0.f);
                C[row * (size_t)N + colb + j * 16] = f2bf(x);
            }
        }
    }
}

// ---------------------------------------------------------------------------
// BatchNorm stats + heads — unchanged (proven).
// ---------------------------------------------------------------------------
__global__ __launch_bounds__(256) void bn_stats_a(
    const float* __restrict__ X, float* __restrict__ psum, float* __restrict__ pss)
{
    const int c  = blockIdx.x * 256 + threadIdx.x;
    const int rb = blockIdx.y;
    float s = 0.f, ss = 0.f;
    const int r0 = rb * 256;
    for (int r = r0; r < r0 + 256; ++r) {
        float v = X[(size_t)r * XW + c];
        s += v; ss = fmaf(v, v, ss);
    }
    psum[rb * XW + c] = s;
    pss [rb * XW + c] = ss;
}

__global__ __launch_bounds__(256) void bn_stats_b(
    const float* __restrict__ psum, const float* __restrict__ pss,
    const float* __restrict__ gamma, const float* __restrict__ beta,
    float* __restrict__ scale, float* __restrict__ shift)
{
    const int c = blockIdx.x * 256 + threadIdx.x;
    float s = 0.f, ss = 0.f;
    for (int rb = 0; rb < 32; ++rb) { s += psum[rb * XW + c]; ss += pss[rb * XW + c]; }
    const float inv = 1.f / (float)BQ;
    const float mean = s * inv;
    const float var  = ss * inv - mean * mean;
    const float sc = gamma[c] * rsqrtf(var + BN_EPS);
    scale[c] = sc;
    shift[c] = beta[c] - mean * sc;
}

__global__ __launch_bounds__(256) void head_kernel(
    const float* __restrict__ X, const float* __restrict__ scale,
    const float* __restrict__ shift, const int* __restrict__ tt,
    const float* __restrict__ Wh1, const float* __restrict__ bh1,
    const float* __restrict__ Wh2, const float* __restrict__ bh2,
    const float* __restrict__ Wh3, const float* __restrict__ bh3,
    float* __restrict__ out)
{
    __shared__ float xs[4][XW];
    __shared__ float y1[4][H1N];
    __shared__ float y2[4][H2N + 2];

    const int t = threadIdx.x;
    const int w = t >> 6;
    const int l = t & 63;
    const int s = blockIdx.x * 4 + w;
    const int d = tt[s];

    #pragma unroll 4
    for (int i = 0; i < XW / 64; ++i) {
        const int c = i * 64 + l;
        xs[w][c] = fmaf(X[(size_t)s * XW + c], scale[c], shift[c]);
    }
    __syncthreads();

    if (l < H1N) {
        const float* W1 = Wh1 + (size_t)d * XW * H1N;
        float acc = bh1[d * H1N + l];
        #pragma unroll 8
        for (int c = 0; c < XW; ++c)
            acc = fmaf(xs[w][c], W1[c * H1N + l], acc);
        y1[w][l] = fmaxf(acc, 0.f);
    }
    __syncthreads();

    if (l < H2N) {
        const float* W2 = Wh2 + (size_t)d * H1N * H2N;
        float acc = bh2[d * H2N + l];
        #pragma unroll
        for (int c = 0; c < H1N; ++c)
            acc = fmaf(y1[w][c], W2[c * H2N + l], acc);
        y2[w][l] = fmaxf(acc, 0.f);
    }
    __syncthreads();

    if (l < NWAY) {
        const float* W3 = Wh3 + (size_t)d * H2N * NWAY;
        float acc = bh3[d * NWAY + l];
        #pragma unroll
        for (int c = 0; c < H2N; ++c)
            acc = fmaf(y2[w][c], W3[c * NWAY + l], acc);
        out[(size_t)s * NWAY + l] = acc;
    }
}

// ---------------------------------------------------------------------------
extern "C" void kernel_launch(void* const* d_in, const int* in_sizes, int n_in,
                              void* d_out, int out_size, void* d_ws, size_t ws_size,
                              hipStream_t stream)
{
    const float* x_s   = (const float*)d_in[0];
    const float* x_p   = (const float*)d_in[1];
    const int*   tt    = (const int*)  d_in[2];
    const int*   dom   = (const int*)  d_in[3];
    const float* W_in  = (const float*)d_in[4];
    const float* b_in  = (const float*)d_in[5];
    const float* W_hid = (const float*)d_in[6];
    const float* b_hid = (const float*)d_in[7];
    const float* W_out = (const float*)d_in[8];
    const float* b_out = (const float*)d_in[9];
    const float* Wp    = (const float*)d_in[10];
    const float* bp    = (const float*)d_in[11];
    const float* gamma = (const float*)d_in[12];
    const float* beta  = (const float*)d_in[13];
    const float* Wh1   = (const float*)d_in[14];
    const float* bh1   = (const float*)d_in[15];
    const float* Wh2   = (const float*)d_in[16];
    const float* bh2   = (const float*)d_in[17];
    const float* Wh3   = (const float*)d_in[18];
    const float* bh3   = (const float*)d_in[19];
    float* out = (float*)d_out;

    const dim3 blk(256);
    char* w = (char*)d_ws;

    const size_t FAST_NEED = 470810624ull;

    if (ws_size >= FAST_NEED) {
        unsigned short* xb    = (unsigned short*)w;                    // 192M
        unsigned short* WinT  = (unsigned short*)(w + 201326592);      // 96M region
        unsigned short* WoutT = (unsigned short*)(w + 201326592);      //  8M
        unsigned short* WpT   = (unsigned short*)(w + 209715200);      // 24M
        unsigned short* actA  = (unsigned short*)(w + 301989888);      // 64M
        unsigned short* actB  = (unsigned short*)(w + 369098752);      // 64M
        float*          X     = (float*)(w + 369098752);               // aliases actB
        unsigned short* WhidT = (unsigned short*)(w + 436207616);      // 32M
        float*          psum  = (float*)(w + 469762048);
        float*          pss   = psum + 32 * XW;
        float*          scale = pss  + 32 * XW;
        float*          shift = scale + XW;

        cvt_bf16<<<dim3(2048), blk, 0, stream>>>(x_s, xb, (long long)BQ * FIN / 8);
        transpose_cvt<<<dim3(SUN/64,  FIN/64), blk, 0, stream>>>(W_in,  WinT,  FIN, SUN,  nullptr);
        transpose_cvt<<<dim3(SUN/64,  SUN/64), blk, 0, stream>>>(W_hid, WhidT, SUN, SUN,  nullptr);

        gemm256<<<dim3(512), dim3(512), 0, stream>>>(xb, WinT, b_in, actA, BQ, SUN, FIN);

        transpose_cvt<<<dim3(HIDN/64, SUN/64), blk, 0, stream>>>(W_out, WoutT, SUN, HIDN, nullptr);
        transpose_cvt<<<dim3(HIDN/64, FIN/64), blk, 0, stream>>>(Wp,    WpT,   FIN, HIDN, dom);
        cvt_bf16<<<dim3(2048), blk, 0, stream>>>(x_p, xb, (long long)BQ * FIN / 8);

        gemm256<<<dim3(512), dim3(512), 0, stream>>>(actA, WhidT, b_hid, actB, BQ, SUN, SUN);
        gemm256<<<dim3(512), dim3(512), 0, stream>>>(actB, WhidT, b_hid, actA, BQ, SUN, SUN);
        gemm256<<<dim3(512), dim3(512), 0, stream>>>(actA, WhidT, b_hid, actB, BQ, SUN, SUN);
        gemm256<<<dim3(512), dim3(512), 0, stream>>>(actB, WhidT, b_hid, actA, BQ, SUN, SUN);

        gemm_mfma<false,true,1><<<dim3(512), blk, 0, stream>>>(
            actA, WoutT, b_out, X, BQ, HIDN, SUN, XW, 0, nullptr, 0);
        gemm_mfma<false,true,2><<<dim3(512), blk, 0, stream>>>(
            xb, WpT, bp, X, BQ, HIDN, FIN, XW, HIDN, dom, HIDN);

        bn_stats_a<<<dim3(XW/256, 32), blk, 0, stream>>>(X, psum, pss);
        bn_stats_b<<<dim3(XW/256),     blk, 0, stream>>>(psum, pss, gamma, beta, scale, shift);
        head_kernel<<<dim3(BQ/4), blk, 0, stream>>>(X, scale, shift, tt,
                                                    Wh1, bh1, Wh2, bh2, Wh3, bh3, out);
        return;
    }

    // ---------------- fallback: 256 MiB path ----------------
    unsigned short* actA  = (unsigned short*)w;
    unsigned short* actB  = (unsigned short*)(w + 67108864);
    float*          X     = (float*)(w + 67108864);
    unsigned short* WinT  = (unsigned short*)(w + 134217728);
    unsigned short* WoutT = (unsigned short*)(w + 134217728);
    unsigned short* WpT   = (unsigned short*)(w + 142606336);
    float*          psum  = (float*)(w + 167772160);
    float*          pss   = psum + 32 * XW;
    float*          scale = pss  + 32 * XW;
    float*          shift = scale + XW;
    unsigned short* WhidT = (unsigned short*)(w + 234881024);

    transpose_cvt<<<dim3(SUN/64,  FIN/64), blk, 0, stream>>>(W_in,  WinT,  FIN, SUN,  nullptr);
    transpose_cvt<<<dim3(SUN/64,  SUN/64), blk, 0, stream>>>(W_hid, WhidT, SUN, SUN,  nullptr);

    gemm_mfma<true,false,1><<<dim3(2048), blk, 0, stream>>>(
        x_s, WinT, b_in, actA, BQ, SUN, FIN, SUN, 0, nullptr, 0);

    transpose_cvt<<<dim3(HIDN/64, SUN/64), blk, 0, stream>>>(W_out, WoutT, SUN, HIDN, nullptr);
    transpose_cvt<<<dim3(HIDN/64, FIN/64), blk, 0, stream>>>(Wp,    WpT,   FIN, HIDN, dom);

    gemm256<<<dim3(512), dim3(512), 0, stream>>>(actA, WhidT, b_hid, actB, BQ, SUN, SUN);
    gemm256<<<dim3(512), dim3(512), 0, stream>>>(actB, WhidT, b_hid, actA, BQ, SUN, SUN);
    gemm256<<<dim3(512), dim3(512), 0, stream>>>(actA, WhidT, b_hid, actB, BQ, SUN, SUN);
    gemm256<<<dim3(512), dim3(512), 0, stream>>>(actB, WhidT, b_hid, actA, BQ, SUN, SUN);

    gemm_mfma<false,true,1><<<dim3(512), blk, 0, stream>>>(
        actA, WoutT, b_out, X, BQ, HIDN, SUN, XW, 0, nullptr, 0);
    gemm_mfma<true,true,2><<<dim3(512), blk, 0, stream>>>(
        x_p, WpT, bp, X, BQ, HIDN, FIN, XW, HIDN, dom, HIDN);

    bn_stats_a<<<dim3(XW/256, 32), blk, 0, stream>>>(X, psum, pss);
    bn_stats_b<<<dim3(XW/256),     blk, 0, stream>>>(psum, pss, gamma, beta, scale, shift);
    head_kernel<<<dim3(BQ/4), blk, 0, stream>>>(X, scale, shift, tt,
                                                Wh1, bh1, Wh2, bh2, Wh3, bh3, out);
}

// Round 6
// 2521.213 us; speedup vs baseline: 12.3007x; 1.0390x over previous
//
#include <hip/hip_runtime.h>
#include <hip/hip_bf16.h>

// Problem constants
#define BQ    8192
#define FIN   12288
#define SUN   4096
#define HIDN  1024
#define XW    2048
#define H1N   28
#define H2N   14
#define NWAY  5
#define BN_EPS 1e-5f
#define LEAKS 0.001f

typedef __bf16 bf16x8 __attribute__((ext_vector_type(8)));
typedef float  f32x4  __attribute__((ext_vector_type(4)));
typedef unsigned short ushort8 __attribute__((ext_vector_type(8)));

__device__ __forceinline__ unsigned short f2bf(float f) {
    unsigned u = __float_as_uint(f);
    unsigned r = u + 0x7fffu + ((u >> 16) & 1u);   // RNE
    return (unsigned short)(r >> 16);
}

// Native packed convert (v_cvt_pk_bf16_f32, RNE — bit-identical to f2bf)
__device__ __forceinline__ ushort8 cvt8(const float4 a, const float4 b) {
    union { __bf16 h[8]; ushort8 u; } r;
    r.h[0] = (__bf16)a.x; r.h[1] = (__bf16)a.y;
    r.h[2] = (__bf16)a.z; r.h[3] = (__bf16)a.w;
    r.h[4] = (__bf16)b.x; r.h[5] = (__bf16)b.y;
    r.h[6] = (__bf16)b.z; r.h[7] = (__bf16)b.w;
    return r.u;
}

#define TO_LDS(p) ((__attribute__((address_space(3))) void*)(p))
#define TO_GLB(p) ((const __attribute__((address_space(1))) void*)(p))

// LDS tile layout: row-major [row][32] bf16 (64 B rows). T2 XOR-swizzle:
// logical k-granule lk (8 elems) of row r lives at phys granule lk ^ ((r>>1)&3).
// gload_lds: LINEAR dest + pre-swizzled GLOBAL source (rule #21); reads XOR
// with (lr>>1)&3.

// ---------------------------------------------------------------------------
// Bulk fp32 -> bf16 convert (grid-stride, 8 elems/thread/iter).
// ---------------------------------------------------------------------------
__global__ __launch_bounds__(256) void cvt_bf16(
    const float* __restrict__ in, unsigned short* __restrict__ out, long long n8)
{
    const long long idx = (long long)blockIdx.x * 256 + threadIdx.x;
    const long long stride = (long long)gridDim.x * 256;
    for (long long i = idx; i < n8; i += stride) {
        const float4 a = ((const float4*)in)[2 * i];
        const float4 b = ((const float4*)in)[2 * i + 1];
        ((ushort8*)out)[i] = cvt8(a, b);
    }
}

// ---------------------------------------------------------------------------
// Transpose + fp32->bf16 convert:  in[R][Cc] f32  ->  out[Cc][R] bf16
// ---------------------------------------------------------------------------
__global__ __launch_bounds__(256) void transpose_cvt(
    const float* __restrict__ in, unsigned short* __restrict__ out,
    int R, int Cc, const int* __restrict__ dom)
{
    if (dom) in += (size_t)(*dom) * (size_t)R * (size_t)Cc;
    __shared__ float tile[64][65];
    const int t  = threadIdx.x;
    const int tr = t >> 4;
    const int tc = t & 15;
    const int c0 = blockIdx.x * 64;
    const int r0 = blockIdx.y * 64;

    #pragma unroll
    for (int q = 0; q < 4; ++q) {
        const int r = r0 + tr + q * 16;
        const float4 v = *(const float4*)&in[(size_t)r * Cc + c0 + tc * 4];
        tile[tc*4+0][tr + q*16] = v.x;
        tile[tc*4+1][tr + q*16] = v.y;
        tile[tc*4+2][tr + q*16] = v.z;
        tile[tc*4+3][tr + q*16] = v.w;
    }
    __syncthreads();
    #pragma unroll
    for (int q = 0; q < 4; ++q) {
        const int c = c0 + tr + q * 16;
        ushort4 o;
        o.x = f2bf(tile[tr + q*16][tc*4+0]);
        o.y = f2bf(tile[tr + q*16][tc*4+1]);
        o.z = f2bf(tile[tr + q*16][tc*4+2]);
        o.w = f2bf(tile[tr + q*16][tc*4+3]);
        *(ushort4*)&out[(size_t)c * R + r0 + tc * 4] = o;
    }
}

// ---------------------------------------------------------------------------
// m97-structure bf16 MFMA GEMM (128x128, 2-barrier) — fp32-A fallback only.
// ---------------------------------------------------------------------------
template<bool A_F32, bool OUT_F32, int ACT>
__global__ __launch_bounds__(256) void gemm_mfma(
    const void* __restrict__ Ap, const unsigned short* __restrict__ Bt,
    const float* __restrict__ bias, void* __restrict__ Cp,
    int M, int N, int K, int ldc, int cc0,
    const int* __restrict__ dom, int biasStride)
{
    __shared__ alignas(16) unsigned short As[128 * 32];
    __shared__ alignas(16) unsigned short Bs[128 * 32];

    const int nbx = N >> 7;
    int wg = blockIdx.x;
    const int nwg = gridDim.x;
    if ((nwg & 7) == 0) {
        const int cpx = nwg >> 3;
        wg = (wg & 7) * cpx + (wg >> 3);
    }
    const int bx = wg % nbx, by = wg / nbx;
    const int row0 = by << 7, col0 = bx << 7;

    const int t  = threadIdx.x;
    const int w  = t >> 6;
    const int l  = t & 63;
    const int wr = w >> 1, wc = w & 1;
    const int lr = l & 15, lk = l >> 4;
    const int rsw = (lr >> 1) & 3;

    f32x4 acc[4][4];
    #pragma unroll
    for (int i = 0; i < 4; ++i)
        #pragma unroll
        for (int j = 0; j < 4; ++j)
            acc[i][j] = (f32x4)(0.f);

    const int srow = l >> 2;
    const int skb  = (((l & 3) ^ ((l >> 3) & 3)) * 16);
    const float* Af = (const float*)Ap;
    const unsigned short* Ab = (const unsigned short*)Ap;

    for (int k0 = 0; k0 < K; k0 += 32) {
        __syncthreads();

        #pragma unroll
        for (int c = 0; c < 2; ++c) {
            const int inst = w * 2 + c;
            const int row  = inst * 16 + srow;
            const char* src = (const char*)Bt +
                (((size_t)(col0 + row) * K + k0) * 2 + skb);
            char* dst = (char*)Bs + inst * 1024;
            __builtin_amdgcn_global_load_lds(TO_GLB(src), TO_LDS(dst), 16, 0, 0);
        }
        if (!A_F32) {
            #pragma unroll
            for (int c = 0; c < 2; ++c) {
                const int inst = w * 2 + c;
                const int row  = inst * 16 + srow;
                const char* src = (const char*)Ab +
                    (((size_t)(row0 + row) * K + k0) * 2 + skb);
                char* dst = (char*)As + inst * 1024;
                __builtin_amdgcn_global_load_lds(TO_GLB(src), TO_LDS(dst), 16, 0, 0);
            }
        } else {
            #pragma unroll
            for (int c = 0; c < 2; ++c) {
                const int ci  = t + 256 * c;
                const int row = ci >> 2;
                const int ko  = (((ci & 3) ^ ((ci >> 3) & 3)) * 8);
                const float* s = Af + (size_t)(row0 + row) * K + k0 + ko;
                const float4 v0 = *(const float4*)s;
                const float4 v1 = *(const float4*)(s + 4);
                *(ushort8*)&As[ci * 8] = cvt8(v0, v1);
            }
        }
        __syncthreads();

        bf16x8 af[4], bfv[4];
        #pragma unroll
        for (int i = 0; i < 4; ++i)
            af[i]  = *(const bf16x8*)&As[(wr*64 + i*16 + lr) * 32 + (lk ^ rsw) * 8];
        #pragma unroll
        for (int j = 0; j < 4; ++j)
            bfv[j] = *(const bf16x8*)&Bs[(wc*64 + j*16 + lr) * 32 + (lk ^ rsw) * 8];
        #pragma unroll
        for (int i = 0; i < 4; ++i)
            #pragma unroll
            for (int j = 0; j < 4; ++j)
                acc[i][j] = __builtin_amdgcn_mfma_f32_16x16x32_bf16(
                    af[i], bfv[j], acc[i][j], 0, 0, 0);
    }

    if (dom) bias += (*dom) * biasStride;
    const int colb = col0 + wc * 64 + lr;
    const int rowb = row0 + wr * 64 + lk * 4;
    float bj[4];
    #pragma unroll
    for (int j = 0; j < 4; ++j) bj[j] = bias[colb + j * 16];

    #pragma unroll
    for (int i = 0; i < 4; ++i) {
        #pragma unroll
        for (int r = 0; r < 4; ++r) {
            const size_t row = rowb + i * 16 + r;
            #pragma unroll
            for (int j = 0; j < 4; ++j) {
                float x = acc[i][j][r] + bj[j];
                if (ACT == 1)      x = fmaxf(x, 0.f);
                else if (ACT == 2) x = (x > 0.f) ? x : LEAKS * x;
                const size_t idx = row * (size_t)ldc + cc0 + colb + j * 16;
                if (OUT_F32) ((float*)Cp)[idx] = x;
                else         ((unsigned short*)Cp)[idx] = f2bf(x);
            }
        }
    }
}

// ---------------------------------------------------------------------------
// gemm256: 256x256 tile, BK=32, 8 waves, triple-buffered LDS, distance-2
// prefetch, counted vmcnt(4), T2 swizzle, T5 setprio. bf16 in/out, relu.
// ---------------------------------------------------------------------------
__global__ __launch_bounds__(512, 2) void gemm256(
    const unsigned short* __restrict__ A, const unsigned short* __restrict__ Bt,
    const float* __restrict__ bias, unsigned short* __restrict__ C,
    int M, int N, int K)
{
    __shared__ alignas(16) unsigned short lds[3][2][256 * 32];  // 96 KiB

    const int nbx = N >> 8;
    int wg = blockIdx.x;
    const int nwg = gridDim.x;
    if ((nwg & 7) == 0) {
        const int cpx = nwg >> 3;
        wg = (wg & 7) * cpx + (wg >> 3);
    }
    const int bx = wg % nbx, by = wg / nbx;
    const int row0 = by << 8, col0 = bx << 8;

    const int t  = threadIdx.x;
    const int w  = t >> 6, l = t & 63;
    const int wr = w >> 2, wc = w & 3;
    const int lr = l & 15, lk = l >> 4;
    const int rsw = (lr >> 1) & 3;
    const int srow = l >> 2;
    const int skel = ((l & 3) ^ ((l >> 3) & 3)) * 8;

    f32x4 acc[8][4];
    #pragma unroll
    for (int i = 0; i < 8; ++i)
        #pragma unroll
        for (int j = 0; j < 4; ++j)
            acc[i][j] = (f32x4)(0.f);

    const int NT = K >> 5;

    #define STAGE256(tile_)  do {                                            \
        const int k0_  = (tile_) << 5;                                       \
        const int buf_ = (tile_) % 3;                                        \
        _Pragma("unroll")                                                    \
        for (int s_ = 0; s_ < 2; ++s_) {                                     \
            const int c_   = w * 2 + s_;                                     \
            const int row_ = c_ * 16 + srow;                                 \
            __builtin_amdgcn_global_load_lds(                                \
                TO_GLB(A + (size_t)(row0 + row_) * K + k0_ + skel),          \
                TO_LDS((char*)&lds[buf_][0][0] + c_ * 1024), 16, 0, 0);      \
            __builtin_amdgcn_global_load_lds(                                \
                TO_GLB(Bt + (size_t)(col0 + row_) * K + k0_ + skel),         \
                TO_LDS((char*)&lds[buf_][1][0] + c_ * 1024), 16, 0, 0);      \
        }                                                                    \
    } while (0)

    STAGE256(0);
    if (NT > 1) {
        STAGE256(1);
        asm volatile("s_waitcnt vmcnt(4)" ::: "memory");
    } else {
        asm volatile("s_waitcnt vmcnt(0)" ::: "memory");
    }
    __builtin_amdgcn_sched_barrier(0);
    __builtin_amdgcn_s_barrier();
    __builtin_amdgcn_sched_barrier(0);

    for (int tt = 0; tt < NT; ++tt) {
        const int buf = tt % 3;
        if (tt + 2 < NT) STAGE256(tt + 2);
        __builtin_amdgcn_sched_barrier(0);

        bf16x8 af[8], bfv[4];
        #pragma unroll
        for (int i = 0; i < 8; ++i)
            af[i]  = *(const bf16x8*)&lds[buf][0][(wr*128 + i*16 + lr) * 32 + (lk ^ rsw) * 8];
        #pragma unroll
        for (int j = 0; j < 4; ++j)
            bfv[j] = *(const bf16x8*)&lds[buf][1][(wc*64 + j*16 + lr) * 32 + (lk ^ rsw) * 8];

        __builtin_amdgcn_s_setprio(1);             // T5
        #pragma unroll
        for (int j = 0; j < 4; ++j)
            #pragma unroll
            for (int i = 0; i < 8; ++i)
                acc[i][j] = __builtin_amdgcn_mfma_f32_16x16x32_bf16(
                    af[i], bfv[j], acc[i][j], 0, 0, 0);
        __builtin_amdgcn_s_setprio(0);

        if (tt + 1 < NT) {
            if (tt + 2 < NT) asm volatile("s_waitcnt vmcnt(4)" ::: "memory");
            else             asm volatile("s_waitcnt vmcnt(0)" ::: "memory");
            __builtin_amdgcn_sched_barrier(0);
            __builtin_amdgcn_s_barrier();
            __builtin_amdgcn_sched_barrier(0);
        }
    }
    #undef STAGE256

    const int colb = col0 + wc * 64 + lr;
    const int rowb = row0 + wr * 128 + lk * 4;
    float bj[4];
    #pragma unroll
    for (int j = 0; j < 4; ++j) bj[j] = bias[colb + j * 16];

    #pragma unroll
    for (int i = 0; i < 8; ++i) {
        #pragma unroll
        for (int r = 0; r < 4; ++r) {
            const size_t row = rowb + i * 16 + r;
            #pragma unroll
            for (int j = 0; j < 4; ++j) {
                float x = fmaxf(acc[i][j][r] + bj[j], 0.f);
                C[row * (size_t)N + colb + j * 16] = f2bf(x);
            }
        }
    }
}

// ---------------------------------------------------------------------------
// gemm128: same proven pipeline (counted vmcnt(4), triple buffer, distance-2,
// T2 swizzle) at 128x128 tile, 4 waves, 48 KiB LDS (2 blocks/CU). For the
// narrow-N GEMMs 6/7. bf16 A, fp32 or bf16 out, ACT 0/1/2, dom-gathered bias.
// ---------------------------------------------------------------------------
template<bool OUT_F32, int ACT>
__global__ __launch_bounds__(256, 2) void gemm128(
    const unsigned short* __restrict__ A, const unsigned short* __restrict__ Bt,
    const float* __restrict__ bias, void* __restrict__ Cp,
    int M, int N, int K, int ldc, int cc0,
    const int* __restrict__ dom, int biasStride)
{
    __shared__ alignas(16) unsigned short lds[3][2][128 * 32];  // 48 KiB

    const int nbx = N >> 7;
    int wg = blockIdx.x;
    const int nwg = gridDim.x;
    if ((nwg & 7) == 0) {
        const int cpx = nwg >> 3;
        wg = (wg & 7) * cpx + (wg >> 3);
    }
    const int bx = wg % nbx, by = wg / nbx;
    const int row0 = by << 7, col0 = bx << 7;

    const int t  = threadIdx.x;
    const int w  = t >> 6, l = t & 63;
    const int wr = w >> 1, wc = w & 1;         // 2x2 waves, 64x64 each
    const int lr = l & 15, lk = l >> 4;
    const int rsw = (lr >> 1) & 3;
    const int srow = l >> 2;
    const int skel = ((l & 3) ^ ((l >> 3) & 3)) * 8;

    f32x4 acc[4][4];
    #pragma unroll
    for (int i = 0; i < 4; ++i)
        #pragma unroll
        for (int j = 0; j < 4; ++j)
            acc[i][j] = (f32x4)(0.f);

    const int NT = K >> 5;

    #define STAGE128(tile_)  do {                                            \
        const int k0_  = (tile_) << 5;                                       \
        const int buf_ = (tile_) % 3;                                        \
        _Pragma("unroll")                                                    \
        for (int s_ = 0; s_ < 2; ++s_) {                                     \
            const int c_   = w * 2 + s_;                                     \
            const int row_ = c_ * 16 + srow;                                 \
            __builtin_amdgcn_global_load_lds(                                \
                TO_GLB(A + (size_t)(row0 + row_) * K + k0_ + skel),          \
                TO_LDS((char*)&lds[buf_][0][0] + c_ * 1024), 16, 0, 0);      \
            __builtin_amdgcn_global_load_lds(                                \
                TO_GLB(Bt + (size_t)(col0 + row_) * K + k0_ + skel),         \
                TO_LDS((char*)&lds[buf_][1][0] + c_ * 1024), 16, 0, 0);      \
        }                                                                    \
    } while (0)

    STAGE128(0);
    if (NT > 1) {
        STAGE128(1);
        asm volatile("s_waitcnt vmcnt(4)" ::: "memory");
    } else {
        asm volatile("s_waitcnt vmcnt(0)" ::: "memory");
    }
    __builtin_amdgcn_sched_barrier(0);
    __builtin_amdgcn_s_barrier();
    __builtin_amdgcn_sched_barrier(0);

    for (int tt = 0; tt < NT; ++tt) {
        const int buf = tt % 3;
        if (tt + 2 < NT) STAGE128(tt + 2);
        __builtin_amdgcn_sched_barrier(0);

        bf16x8 af[4], bfv[4];
        #pragma unroll
        for (int i = 0; i < 4; ++i)
            af[i]  = *(const bf16x8*)&lds[buf][0][(wr*64 + i*16 + lr) * 32 + (lk ^ rsw) * 8];
        #pragma unroll
        for (int j = 0; j < 4; ++j)
            bfv[j] = *(const bf16x8*)&lds[buf][1][(wc*64 + j*16 + lr) * 32 + (lk ^ rsw) * 8];

        #pragma unroll
        for (int j = 0; j < 4; ++j)
            #pragma unroll
            for (int i = 0; i < 4; ++i)
                acc[i][j] = __builtin_amdgcn_mfma_f32_16x16x32_bf16(
                    af[i], bfv[j], acc[i][j], 0, 0, 0);

        if (tt + 1 < NT) {
            if (tt + 2 < NT) asm volatile("s_waitcnt vmcnt(4)" ::: "memory");
            else             asm volatile("s_waitcnt vmcnt(0)" ::: "memory");
            __builtin_amdgcn_sched_barrier(0);
            __builtin_amdgcn_s_barrier();
            __builtin_amdgcn_sched_barrier(0);
        }
    }
    #undef STAGE128

    if (dom) bias += (*dom) * biasStride;
    const int colb = col0 + wc * 64 + lr;
    const int rowb = row0 + wr * 64 + lk * 4;
    float bj[4];
    #pragma unroll
    for (int j = 0; j < 4; ++j) bj[j] = bias[colb + j * 16];

    #pragma unroll
    for (int i = 0; i < 4; ++i) {
        #pragma unroll
        for (int r = 0; r < 4; ++r) {
            const size_t row = rowb + i * 16 + r;
            #pragma unroll
            for (int j = 0; j < 4; ++j) {
                float x = acc[i][j][r] + bj[j];
                if (ACT == 1)      x = fmaxf(x, 0.f);
                else if (ACT == 2) x = (x > 0.f) ? x : LEAKS * x;
                const size_t idx = row * (size_t)ldc + cc0 + colb + j * 16;
                if (OUT_F32) ((float*)Cp)[idx] = x;
                else         ((unsigned short*)Cp)[idx] = f2bf(x);
            }
        }
    }
}

// ---------------------------------------------------------------------------
// BatchNorm stats + heads — unchanged (proven).
// ---------------------------------------------------------------------------
__global__ __launch_bounds__(256) void bn_stats_a(
    const float* __restrict__ X, float* __restrict__ psum, float* __restrict__ pss)
{
    const int c  = blockIdx.x * 256 + threadIdx.x;
    const int rb = blockIdx.y;
    float s = 0.f, ss = 0.f;
    const int r0 = rb * 256;
    for (int r = r0; r < r0 + 256; ++r) {
        float v = X[(size_t)r * XW + c];
        s += v; ss = fmaf(v, v, ss);
    }
    psum[rb * XW + c] = s;
    pss [rb * XW + c] = ss;
}

__global__ __launch_bounds__(256) void bn_stats_b(
    const float* __restrict__ psum, const float* __restrict__ pss,
    const float* __restrict__ gamma, const float* __restrict__ beta,
    float* __restrict__ scale, float* __restrict__ shift)
{
    const int c = blockIdx.x * 256 + threadIdx.x;
    float s = 0.f, ss = 0.f;
    for (int rb = 0; rb < 32; ++rb) { s += psum[rb * XW + c]; ss += pss[rb * XW + c]; }
    const float inv = 1.f / (float)BQ;
    const float mean = s * inv;
    const float var  = ss * inv - mean * mean;
    const float sc = gamma[c] * rsqrtf(var + BN_EPS);
    scale[c] = sc;
    shift[c] = beta[c] - mean * sc;
}

__global__ __launch_bounds__(256) void head_kernel(
    const float* __restrict__ X, const float* __restrict__ scale,
    const float* __restrict__ shift, const int* __restrict__ tt,
    const float* __restrict__ Wh1, const float* __restrict__ bh1,
    const float* __restrict__ Wh2, const float* __restrict__ bh2,
    const float* __restrict__ Wh3, const float* __restrict__ bh3,
    float* __restrict__ out)
{
    __shared__ float xs[4][XW];
    __shared__ float y1[4][H1N];
    __shared__ float y2[4][H2N + 2];

    const int t = threadIdx.x;
    const int w = t >> 6;
    const int l = t & 63;
    const int s = blockIdx.x * 4 + w;
    const int d = tt[s];

    #pragma unroll 4
    for (int i = 0; i < XW / 64; ++i) {
        const int c = i * 64 + l;
        xs[w][c] = fmaf(X[(size_t)s * XW + c], scale[c], shift[c]);
    }
    __syncthreads();

    if (l < H1N) {
        const float* W1 = Wh1 + (size_t)d * XW * H1N;
        float acc = bh1[d * H1N + l];
        #pragma unroll 8
        for (int c = 0; c < XW; ++c)
            acc = fmaf(xs[w][c], W1[c * H1N + l], acc);
        y1[w][l] = fmaxf(acc, 0.f);
    }
    __syncthreads();

    if (l < H2N) {
        const float* W2 = Wh2 + (size_t)d * H1N * H2N;
        float acc = bh2[d * H2N + l];
        #pragma unroll
        for (int c = 0; c < H1N; ++c)
            acc = fmaf(y1[w][c], W2[c * H2N + l], acc);
        y2[w][l] = fmaxf(acc, 0.f);
    }
    __syncthreads();

    if (l < NWAY) {
        const float* W3 = Wh3 + (size_t)d * H2N * NWAY;
        float acc = bh3[d * NWAY + l];
        #pragma unroll
        for (int c = 0; c < H2N; ++c)
            acc = fmaf(y2[w][c], W3[c * NWAY + l], acc);
        out[(size_t)s * NWAY + l] = acc;
    }
}

// ---------------------------------------------------------------------------
extern "C" void kernel_launch(void* const* d_in, const int* in_sizes, int n_in,
                              void* d_out, int out_size, void* d_ws, size_t ws_size,
                              hipStream_t stream)
{
    const float* x_s   = (const float*)d_in[0];
    const float* x_p   = (const float*)d_in[1];
    const int*   tt    = (const int*)  d_in[2];
    const int*   dom   = (const int*)  d_in[3];
    const float* W_in  = (const float*)d_in[4];
    const float* b_in  = (const float*)d_in[5];
    const float* W_hid = (const float*)d_in[6];
    const float* b_hid = (const float*)d_in[7];
    const float* W_out = (const float*)d_in[8];
    const float* b_out = (const float*)d_in[9];
    const float* Wp    = (const float*)d_in[10];
    const float* bp    = (const float*)d_in[11];
    const float* gamma = (const float*)d_in[12];
    const float* beta  = (const float*)d_in[13];
    const float* Wh1   = (const float*)d_in[14];
    const float* bh1   = (const float*)d_in[15];
    const float* Wh2   = (const float*)d_in[16];
    const float* bh2   = (const float*)d_in[17];
    const float* Wh3   = (const float*)d_in[18];
    const float* bh3   = (const float*)d_in[19];
    float* out = (float*)d_out;

    const dim3 blk(256);
    char* w = (char*)d_ws;

    const size_t FAST_NEED = 470810624ull;

    if (ws_size >= FAST_NEED) {
        unsigned short* xb    = (unsigned short*)w;                    // 192M
        unsigned short* WinT  = (unsigned short*)(w + 201326592);      // 96M region
        unsigned short* WoutT = (unsigned short*)(w + 201326592);      //  8M
        unsigned short* WpT   = (unsigned short*)(w + 209715200);      // 24M
        unsigned short* actA  = (unsigned short*)(w + 301989888);      // 64M
        unsigned short* actB  = (unsigned short*)(w + 369098752);      // 64M
        float*          X     = (float*)(w + 369098752);               // aliases actB
        unsigned short* WhidT = (unsigned short*)(w + 436207616);      // 32M
        float*          psum  = (float*)(w + 469762048);
        float*          pss   = psum + 32 * XW;
        float*          scale = pss  + 32 * XW;
        float*          shift = scale + XW;

        cvt_bf16<<<dim3(2048), blk, 0, stream>>>(x_s, xb, (long long)BQ * FIN / 8);
        transpose_cvt<<<dim3(SUN/64,  FIN/64), blk, 0, stream>>>(W_in,  WinT,  FIN, SUN,  nullptr);
        transpose_cvt<<<dim3(SUN/64,  SUN/64), blk, 0, stream>>>(W_hid, WhidT, SUN, SUN,  nullptr);

        gemm256<<<dim3(512), dim3(512), 0, stream>>>(xb, WinT, b_in, actA, BQ, SUN, FIN);

        transpose_cvt<<<dim3(HIDN/64, SUN/64), blk, 0, stream>>>(W_out, WoutT, SUN, HIDN, nullptr);
        transpose_cvt<<<dim3(HIDN/64, FIN/64), blk, 0, stream>>>(Wp,    WpT,   FIN, HIDN, dom);
        cvt_bf16<<<dim3(2048), blk, 0, stream>>>(x_p, xb, (long long)BQ * FIN / 8);

        gemm256<<<dim3(512), dim3(512), 0, stream>>>(actA, WhidT, b_hid, actB, BQ, SUN, SUN);
        gemm256<<<dim3(512), dim3(512), 0, stream>>>(actB, WhidT, b_hid, actA, BQ, SUN, SUN);
        gemm256<<<dim3(512), dim3(512), 0, stream>>>(actA, WhidT, b_hid, actB, BQ, SUN, SUN);
        gemm256<<<dim3(512), dim3(512), 0, stream>>>(actB, WhidT, b_hid, actA, BQ, SUN, SUN);

        // GEMM6/7 via the pipelined 128^2 kernel
        gemm128<true,1><<<dim3(512), blk, 0, stream>>>(
            actA, WoutT, b_out, X, BQ, HIDN, SUN, XW, 0, nullptr, 0);
        gemm128<true,2><<<dim3(512), blk, 0, stream>>>(
            xb, WpT, bp, X, BQ, HIDN, FIN, XW, HIDN, dom, HIDN);

        bn_stats_a<<<dim3(XW/256, 32), blk, 0, stream>>>(X, psum, pss);
        bn_stats_b<<<dim3(XW/256),     blk, 0, stream>>>(psum, pss, gamma, beta, scale, shift);
        head_kernel<<<dim3(BQ/4), blk, 0, stream>>>(X, scale, shift, tt,
                                                    Wh1, bh1, Wh2, bh2, Wh3, bh3, out);
        return;
    }

    // ---------------- fallback: 256 MiB path ----------------
    unsigned short* actA  = (unsigned short*)w;
    unsigned short* actB  = (unsigned short*)(w + 67108864);
    float*          X     = (float*)(w + 67108864);
    unsigned short* WinT  = (unsigned short*)(w + 134217728);
    unsigned short* WoutT = (unsigned short*)(w + 134217728);
    unsigned short* WpT   = (unsigned short*)(w + 142606336);
    float*          psum  = (float*)(w + 167772160);
    float*          pss   = psum + 32 * XW;
    float*          scale = pss  + 32 * XW;
    float*          shift = scale + XW;
    unsigned short* WhidT = (unsigned short*)(w + 234881024);

    transpose_cvt<<<dim3(SUN/64,  FIN/64), blk, 0, stream>>>(W_in,  WinT,  FIN, SUN,  nullptr);
    transpose_cvt<<<dim3(SUN/64,  SUN/64), blk, 0, stream>>>(W_hid, WhidT, SUN, SUN,  nullptr);

    gemm_mfma<true,false,1><<<dim3(2048), blk, 0, stream>>>(
        x_s, WinT, b_in, actA, BQ, SUN, FIN, SUN, 0, nullptr, 0);

    transpose_cvt<<<dim3(HIDN/64, SUN/64), blk, 0, stream>>>(W_out, WoutT, SUN, HIDN, nullptr);
    transpose_cvt<<<dim3(HIDN/64, FIN/64), blk, 0, stream>>>(Wp,    WpT,   FIN, HIDN, dom);

    gemm256<<<dim3(512), dim3(512), 0, stream>>>(actA, WhidT, b_hid, actB, BQ, SUN, SUN);
    gemm256<<<dim3(512), dim3(512), 0, stream>>>(actB, WhidT, b_hid, actA, BQ, SUN, SUN);
    gemm256<<<dim3(512), dim3(512), 0, stream>>>(actA, WhidT, b_hid, actB, BQ, SUN, SUN);
    gemm256<<<dim3(512), dim3(512), 0, stream>>>(actB, WhidT, b_hid, actA, BQ, SUN, SUN);

    gemm128<true,1><<<dim3(512), blk, 0, stream>>>(
        actA, WoutT, b_out, X, BQ, HIDN, SUN, XW, 0, nullptr, 0);
    gemm_mfma<true,true,2><<<dim3(512), blk, 0, stream>>>(
        x_p, WpT, bp, X, BQ, HIDN, FIN, XW, HIDN, dom, HIDN);

    bn_stats_a<<<dim3(XW/256, 32), blk, 0, stream>>>(X, psum, pss);
    bn_stats_b<<<dim3(XW/256),     blk, 0, stream>>>(psum, pss, gamma, beta, scale, shift);
    head_kernel<<<dim3(BQ/4), blk, 0, stream>>>(X, scale, shift, tt,
                                                Wh1, bh1, Wh2, bh2, Wh3, bh3, out);
}